// Round 14
// baseline (638.999 us; speedup 1.0000x reference)
//
#include <hip/hip_runtime.h>
#include <hip/hip_bf16.h>
#include <math.h>

#define N_NODES 2048
#define NEDGE   65536
#define FDIM    128
#define HDIM    512
#define EFD     16
#define EDD     64
#define LPATH   5
#define NLAYER  4
#define NHEAD   8
#define DK      64
#define ODIM    64
#define MAXDEG  64
#define PTOT    4194304
#define LOG2E   1.4426950408889634f

typedef __bf16 bf16;
typedef bf16 bf16x8 __attribute__((ext_vector_type(8)));
typedef bf16 bf16x4 __attribute__((ext_vector_type(4)));
typedef float f32x4 __attribute__((ext_vector_type(4)));
typedef unsigned short u16;

// ---------------- fused prep: blocks [0,256) = edge weights + degrees; [256,1920) = weight transposes ----------------
__global__ __launch_bounds__(256) void k_prep(const float* __restrict__ ea, const float* __restrict__ We,
                                              const float* __restrict__ be, const float* __restrict__ ev,
                                              const int* __restrict__ ei, int* __restrict__ din,
                                              int* __restrict__ dout, bf16* __restrict__ wT,
                                              const float* __restrict__ Wq, const float* __restrict__ Wk,
                                              const float* __restrict__ Wv, const float* __restrict__ Wo,
                                              const float* __restrict__ W1, const float* __restrict__ W2,
                                              const float* __restrict__ Wn, const float* __restrict__ Wout,
                                              bf16* __restrict__ Wt, bf16* __restrict__ WnT,
                                              bf16* __restrict__ WoutT) {
    __shared__ float sM[80];
    __shared__ float sc[8];
    __shared__ float Ls[64][68];
    int t = threadIdx.x;
    int bx = blockIdx.x;
    if (bx < 256) {
        if (t < 80) {
            int i = t / 5, j = t % 5;
            float acc = 0.f;
            for (int k = 0; k < EDD; ++k) acc += We[i * EDD + k] * ev[j * EDD + k];
            sM[t] = acc;
        } else if (t >= 128 && t < 128 + LPATH) {
            int j = t - 128;
            float acc = 0.f;
            for (int k = 0; k < EDD; ++k) acc += be[k] * ev[j * EDD + k];
            sc[j] = acc;
        }
        int e = bx * 256 + t;
        atomicAdd(&dout[ei[e]], 1);
        atomicAdd(&din[ei[NEDGE + e]], 1);
        __syncthreads();
        const float4* p = (const float4*)(ea + (size_t)e * EFD);
        float4 a0 = p[0], a1 = p[1], a2 = p[2], a3 = p[3];
        float a[16] = {a0.x, a0.y, a0.z, a0.w, a1.x, a1.y, a1.z, a1.w,
                       a2.x, a2.y, a2.z, a2.w, a3.x, a3.y, a3.z, a3.w};
        float out[LPATH];
#pragma unroll
        for (int j = 0; j < LPATH; ++j) out[j] = sc[j];
#pragma unroll
        for (int i = 0; i < 16; ++i)
#pragma unroll
            for (int j = 0; j < LPATH; ++j) out[j] += a[i] * sM[i * LPATH + j];
#pragma unroll
        for (int j = 0; j < LPATH; ++j) wT[(size_t)j * NEDGE + e] = (bf16)out[j];
        return;
    }
    int m = (bx - 256) >> 6;
    int q = (bx - 256) & 63;
    int rr = t >> 4, cc = t & 15;
    int nl = t >> 2, kc = t & 3;
    if (m < 24) {
        int lay = m / 6, type = m % 6;
        const float* src = type == 0 ? Wq : type == 1 ? Wk : type == 2 ? Wv : type == 3 ? Wo : type == 4 ? W1 : W2;
        src += (size_t)lay * (HDIM * HDIM);
        int tk = q >> 3, tn = q & 7;
#pragma unroll
        for (int u = 0; u < 4; ++u) {
            float4 v = *(const float4*)(src + (size_t)(tk * 64 + rr + 16 * u) * HDIM + tn * 64 + cc * 4);
            *(float4*)&Ls[rr + 16 * u][cc * 4] = v;
        }
        __syncthreads();
        bf16 tmp[16];
#pragma unroll
        for (int u = 0; u < 16; ++u) tmp[u] = (bf16)Ls[kc * 16 + u][nl];
        bf16* dst = Wt + (size_t)m * (HDIM * HDIM) + (size_t)(tn * 64 + nl) * HDIM + tk * 64 + kc * 16;
        *(bf16x8*)(dst) = *(bf16x8*)&tmp[0];
        *(bf16x8*)(dst + 8) = *(bf16x8*)&tmp[8];
    } else if (m == 24) {
        if (q >= 16) return;
        int tk = q >> 3, tn = q & 7;
#pragma unroll
        for (int u = 0; u < 4; ++u) {
            float4 v = *(const float4*)(Wn + (size_t)(tk * 64 + rr + 16 * u) * HDIM + tn * 64 + cc * 4);
            *(float4*)&Ls[rr + 16 * u][cc * 4] = v;
        }
        __syncthreads();
        bf16 tmp[16];
#pragma unroll
        for (int u = 0; u < 16; ++u) tmp[u] = (bf16)Ls[kc * 16 + u][nl];
        bf16* dst = WnT + (size_t)(tn * 64 + nl) * FDIM + tk * 64 + kc * 16;
        *(bf16x8*)dst = *(bf16x8*)&tmp[0];
        *(bf16x8*)(dst + 8) = *(bf16x8*)&tmp[8];
    } else {
        if (q >= 8) return;
        int tk = q;
#pragma unroll
        for (int u = 0; u < 4; ++u) {
            float4 v = *(const float4*)(Wout + (size_t)(tk * 64 + rr + 16 * u) * ODIM + cc * 4);
            *(float4*)&Ls[rr + 16 * u][cc * 4] = v;
        }
        __syncthreads();
        bf16 tmp[16];
#pragma unroll
        for (int u = 0; u < 16; ++u) tmp[u] = (bf16)Ls[kc * 16 + u][nl];
        bf16* dst = WoutT + (size_t)nl * HDIM + tk * 64 + kc * 16;
        *(bf16x8*)dst = *(bf16x8*)&tmp[0];
        *(bf16x8*)(dst + 8) = *(bf16x8*)&tmp[8];
    }
}

// ---------------- bias: r8 structure (single 8192-pair chunk, spill-free). Output bias * LOG2E ----------------
__global__ __launch_bounds__(1024) void k_bias3(const int* __restrict__ ep, const bf16* __restrict__ wT,
                                                const float* __restrict__ bsp, bf16* __restrict__ bias) {
    __shared__ char lds[163840];
    int t = threadIdx.x;
    size_t basep = (size_t)blockIdx.x * 8192;
    int* ish = (int*)lds;
    const int4* src = (const int4*)(ep + basep * 5);
#pragma unroll
    for (int u = 0; u < 10; ++u) ((int4*)ish)[t + 1024 * u] = src[t + 1024 * u];
    __syncthreads();
    unsigned pa[8], pb[8], pc[8];
#pragma unroll
    for (int r = 0; r < 8; ++r) {
        int p5 = (r * 1024 + t) * 5;
        int e0 = ish[p5], e1 = ish[p5 + 1], e2 = ish[p5 + 2], e3 = ish[p5 + 3], e4 = ish[p5 + 4];
        unsigned mk = (unsigned)(e0 >= 0) | ((unsigned)(e1 >= 0) << 1) | ((unsigned)(e2 >= 0) << 2)
                    | ((unsigned)(e3 >= 0) << 3) | ((unsigned)(e4 >= 0) << 4);
        pa[r] = ((unsigned)e0 & 0xFFFFu) | ((unsigned)e1 << 16);
        pb[r] = ((unsigned)e2 & 0xFFFFu) | ((unsigned)e3 << 16);
        pc[r] = ((unsigned)e4 & 0xFFFFu) | (mk << 16);
    }
    bf16* wsl = (bf16*)lds;
    float csum[8] = {};
#pragma unroll
    for (int l = 0; l < LPATH; ++l) {
        __syncthreads();
#pragma unroll
        for (int u = 0; u < 4; ++u) {
            int o = u * 16384 + t * 16;
            *(bf16x8*)&wsl[o]     = *(const bf16x8*)&wT[(size_t)l * NEDGE + o];
            *(bf16x8*)&wsl[o + 8] = *(const bf16x8*)&wT[(size_t)l * NEDGE + o + 8];
        }
        __syncthreads();
#pragma unroll
        for (int r = 0; r < 8; ++r) {
            unsigned ix = (l == 0) ? (pa[r] & 0xFFFFu) : (l == 1) ? (pa[r] >> 16)
                        : (l == 2) ? (pb[r] & 0xFFFFu) : (l == 3) ? (pb[r] >> 16) : (pc[r] & 0xFFFFu);
            float v = (float)wsl[ix];
            csum[r] += ((pc[r] >> (16 + l)) & 1u) ? v : 0.f;
        }
    }
#pragma unroll
    for (int r = 0; r < 8; ++r) {
        int cnt = __popc((int)((pc[r] >> 16) & 0x1Fu));
        float b = cnt ? (bsp[cnt - 1] + csum[r] / (float)cnt) * LOG2E : 0.f;
        bias[basep + r * 1024 + t] = (bf16)b;
    }
}

// node projection as MFMA GEMM (K=128, f32 x inline-cast) + degree-embedding epilogue
__global__ __launch_bounds__(256) void k_nmm(const float* __restrict__ x, const bf16* __restrict__ Bt,
                                             const float* __restrict__ bn, const float* __restrict__ zin,
                                             const float* __restrict__ zout, const int* __restrict__ din,
                                             const int* __restrict__ dout, float* __restrict__ h) {
    __shared__ bf16 Bs[8192];
    int t = threadIdx.x, w = t >> 6, l = t & 63, lr = l & 15, lg = l >> 4;
    int j0 = blockIdx.x * 64, i0 = blockIdx.y * 64;
    const bf16* Bp = Bt + (size_t)j0 * FDIM;
#pragma unroll
    for (int rnd = 0; rnd < 4; ++rnd) {
        int tt = rnd * 256 + t;
        int ks = tt >> 8, qq = (tt >> 6) & 3, mm = (tt >> 2) & 15, gg = tt & 3;
        *(bf16x8*)(Bs + tt * 8) = *(const bf16x8*)(Bp + (size_t)(qq * 16 + mm) * FDIM + ks * 32 + gg * 8);
    }
    __syncthreads();
    const float* ap = x + (size_t)(i0 + w * 16 + lr) * FDIM + 8 * lg;
    f32x4 acc[4] = {};
#pragma unroll
    for (int ks = 0; ks < 4; ++ks) {
        float4 f0 = *(const float4*)(ap + ks * 32);
        float4 f1 = *(const float4*)(ap + ks * 32 + 4);
        bf16x8 a;
        a[0] = (bf16)f0.x; a[1] = (bf16)f0.y; a[2] = (bf16)f0.z; a[3] = (bf16)f0.w;
        a[4] = (bf16)f1.x; a[5] = (bf16)f1.y; a[6] = (bf16)f1.z; a[7] = (bf16)f1.w;
        const bf16* bb = Bs + ks * 2048 + lr * 32 + lg * 8;
#pragma unroll
        for (int sub = 0; sub < 4; ++sub)
            acc[sub] = __builtin_amdgcn_mfma_f32_16x16x32_bf16(a, *(const bf16x8*)(bb + sub * 512), acc[sub], 0, 0, 0);
    }
#pragma unroll
    for (int r = 0; r < 4; ++r) {
        int i = i0 + w * 16 + lg * 4 + r;
        int di = min(din[i], MAXDEG - 1), dz = min(dout[i], MAXDEG - 1);
#pragma unroll
        for (int sub = 0; sub < 4; ++sub) {
            int j = j0 + sub * 16 + lr;
            h[(size_t)i * HDIM + j] = acc[sub][r] + bn[j] + zin[(size_t)di * HDIM + j] + zout[(size_t)dz * HDIM + j];
        }
    }
}

// ---------------- LN1 + QKV fused: per-block two-pass LN into frag-contiguous LDS A, then GEMM ----------------
// q pre-scaled by 0.125*LOG2E (attn softmax in exp2 domain)
__global__ __launch_bounds__(256) void k_lnqkv(const float* __restrict__ h, const bf16* __restrict__ Wt_l,
                                               const float* __restrict__ lnS, const float* __restrict__ lnB,
                                               const float* __restrict__ bq, const float* __restrict__ bk,
                                               const float* __restrict__ bv, bf16* __restrict__ qf,
                                               bf16* __restrict__ kf, bf16* __restrict__ vf) {
    __shared__ bf16 As[32768];   // 64 rows x 512, frag-contiguous
    __shared__ bf16 Bs[16384];
    __shared__ float sbuf[HDIM], bbuf[HDIM];
    int t = threadIdx.x, w = t >> 6, l = t & 63, lr = l & 15, lg = l >> 4;
    int j0 = blockIdx.x * 32, i0 = blockIdx.y * 64;
    int type = j0 >> 9, n0 = j0 & 511;
    sbuf[t] = lnS[t]; sbuf[t + 256] = lnS[t + 256];
    bbuf[t] = lnB[t]; bbuf[t + 256] = lnB[t + 256];
    const bf16* Bp = Wt_l + (size_t)type * (HDIM * HDIM) + (size_t)n0 * HDIM;
#pragma unroll
    for (int rnd = 0; rnd < 8; ++rnd) {
        int tt = rnd * 256 + t;
        int ks = tt >> 7, qq = (tt >> 6) & 1, mm = (tt >> 2) & 15, gg = tt & 3;
        *(bf16x8*)(Bs + tt * 8) = *(const bf16x8*)(Bp + (size_t)(qq * 16 + mm) * HDIM + ks * 32 + gg * 8);
    }
    // LN pass 1: stats (4 lanes per row, 128 cols each)
    int row = t >> 2, c4 = t & 3;
    const float* hp = h + (size_t)(i0 + row) * HDIM + c4 * 128;
    float S = 0.f, Q = 0.f;
#pragma unroll
    for (int u = 0; u < 32; ++u) {
        float4 v = *(const float4*)(hp + u * 4);
        S += v.x + v.y + v.z + v.w;
        Q += v.x * v.x + v.y * v.y + v.z * v.z + v.w * v.w;
    }
    S += __shfl_xor(S, 1); Q += __shfl_xor(Q, 1);
    S += __shfl_xor(S, 2); Q += __shfl_xor(Q, 2);
    float mean = S * (1.f / HDIM);
    float var = Q * (1.f / HDIM) - mean * mean;
    float rn = rsqrtf(var + 1e-5f);
    float ca = rn, cc = -mean * rn;
    __syncthreads();   // sbuf/bbuf ready
    // LN pass 2: normalize (L1-resident reload) into As
    bf16* asr = As + (row >> 4) * 8192 + (row & 15) * 32;
#pragma unroll
    for (int u = 0; u < 16; ++u) {
        int c = c4 * 128 + u * 8;
        float4 v0 = *(const float4*)(hp + u * 8);
        float4 v1 = *(const float4*)(hp + u * 8 + 4);
        float vv[8] = {v0.x, v0.y, v0.z, v0.w, v1.x, v1.y, v1.z, v1.w};
        bf16x8 o;
#pragma unroll
        for (int j = 0; j < 8; ++j) o[j] = (bf16)fmaf(fmaf(vv[j], ca, cc), sbuf[c + j], bbuf[c + j]);
        *(bf16x8*)(asr + ((c >> 5) * 512) + (c & 31)) = o;
    }
    __syncthreads();   // As + Bs ready
    const bf16* apl = As + w * 8192 + lr * 32 + lg * 8;
    const float* bvec = (type == 0 ? bq : type == 1 ? bk : bv);
    f32x4 acc[2] = {};
#pragma unroll 4
    for (int ks = 0; ks < 16; ++ks) {
        bf16x8 a = *(const bf16x8*)(apl + ks * 512);
        const bf16* bb = Bs + ks * 1024 + lr * 32 + lg * 8;
        bf16x8 b0 = *(const bf16x8*)(bb);
        bf16x8 b1 = *(const bf16x8*)(bb + 512);
        acc[0] = __builtin_amdgcn_mfma_f32_16x16x32_bf16(a, b0, acc[0], 0, 0, 0);
        acc[1] = __builtin_amdgcn_mfma_f32_16x16x32_bf16(a, b1, acc[1], 0, 0, 0);
    }
    int hh = n0 >> 6;
    if (type < 2) {
        bf16* dst = (type == 0 ? qf : kf);
        int hf = (n0 & 32) >> 5;
        float scq = (type == 0 ? 0.125f * LOG2E : 1.0f);
#pragma unroll
        for (int sub = 0; sub < 2; ++sub) {
#pragma unroll
            for (int r = 0; r < 4; ++r) {
                int i = i0 + w * 16 + lg * 4 + r;
                float v = (acc[sub][r] + bvec[n0 + sub * 16 + lr]) * scq;
                int lgp = sub * 2 + (lr >> 3);
                size_t off = (((size_t)(hh * 128 + (i >> 4)) * 2 + hf) << 9) + lgp * 128 + (lg * 4 + r) * 8 + (lr & 7);
                dst[off] = (bf16)v;
            }
        }
    } else {
#pragma unroll
        for (int sub = 0; sub < 2; ++sub) {
#pragma unroll
            for (int r = 0; r < 4; ++r) {
                int node = i0 + w * 16 + lg * 4 + r;
                int dd = (n0 & 63) + sub * 16 + lr;
                float v = acc[sub][r] + bvec[n0 + sub * 16 + lr];
                size_t off = (((size_t)(hh * 4 + (dd >> 4)) * 64 + (node >> 5)) << 9)
                           + ((node >> 3) & 3) * 128 + (dd & 15) * 8 + (node & 7);
                vf[off] = (bf16)v;
            }
        }
    }
}

// ---------------- generic bf16 MFMA GEMM, BN=64, 16 waves, 4-way K-split ----------------
#define FL_RES   1
#define FL_GELU  2
#define FL_OUTF  4

__device__ inline float gelu_f(float x) {
    float x3 = x * x * x;
    float u = 0.7978845608028654f * (x + 0.044715f * x3);
    return 0.5f * x * (1.f + tanhf(u));
}

__global__ __launch_bounds__(1024) void k_mm(const bf16* __restrict__ A, const bf16* __restrict__ Bt,
                                             const float* __restrict__ bvec, const float* __restrict__ res,
                                             float* __restrict__ outF, bf16* __restrict__ outB, int flags) {
    __shared__ bf16 Bs[32768];
    __shared__ float Osh[4][16][68];
    int t = threadIdx.x, w = t >> 6, l = t & 63, lr = l & 15, lg = l >> 4;
    int ti = w & 3, s = w >> 2;
    int j0 = blockIdx.x * 64, i0 = blockIdx.y * 64;
    const bf16* Bp = Bt + (size_t)j0 * HDIM;
#pragma unroll
    for (int rnd = 0; rnd < 4; ++rnd) {
        int tt = rnd * 1024 + t;
        int ks = tt >> 8, qq = (tt >> 6) & 3, mm = (tt >> 2) & 15, gg = tt & 3;
        bf16x8 v = *(const bf16x8*)(Bp + (size_t)(qq * 16 + mm) * HDIM + ks * 32 + gg * 8);
        *(bf16x8*)(Bs + tt * 8) = v;
    }
    __syncthreads();
    const bf16* ap = A + (size_t)(i0 + ti * 16 + lr) * HDIM + 8 * lg;
    f32x4 acc[4] = {};
#pragma unroll
    for (int kk = 0; kk < 4; ++kk) {
        int ks = s * 4 + kk;
        bf16x8 a = *(const bf16x8*)(ap + ks * 32);
        const bf16* bb = Bs + ks * 2048 + lr * 32 + lg * 8;
#pragma unroll
        for (int sub = 0; sub < 4; ++sub) {
            bf16x8 b = *(const bf16x8*)(bb + sub * 512);
            acc[sub] = __builtin_amdgcn_mfma_f32_16x16x32_bf16(a, b, acc[sub], 0, 0, 0);
        }
    }
    if (s == 0) {
#pragma unroll
        for (int sub = 0; sub < 4; ++sub)
#pragma unroll
            for (int r = 0; r < 4; ++r) Osh[ti][lg * 4 + r][sub * 16 + lr] = acc[sub][r];
    }
    __syncthreads();
    if (s == 1) {
#pragma unroll
        for (int sub = 0; sub < 4; ++sub)
#pragma unroll
            for (int r = 0; r < 4; ++r) Osh[ti][lg * 4 + r][sub * 16 + lr] += acc[sub][r];
    }
    __syncthreads();
    if (s == 2) {
#pragma unroll
        for (int sub = 0; sub < 4; ++sub)
#pragma unroll
            for (int r = 0; r < 4; ++r) Osh[ti][lg * 4 + r][sub * 16 + lr] += acc[sub][r];
    }
    __syncthreads();
    if (s == 3) {
#pragma unroll
        for (int sub = 0; sub < 4; ++sub) {
#pragma unroll
            for (int r = 0; r < 4; ++r) {
                int i = i0 + ti * 16 + lg * 4 + r;
                int j = j0 + sub * 16 + lr;
                float v = Osh[ti][lg * 4 + r][sub * 16 + lr] + acc[sub][r] + bvec[j];
                if (flags & FL_RES) v += res[(size_t)i * HDIM + j];
                if (flags & FL_GELU) v = gelu_f(v);
                if (flags & FL_OUTF) outF[(size_t)i * HDIM + j] = v;
                else outB[(size_t)i * HDIM + j] = (bf16)v;
            }
        }
    }
}

// ---------------- LN2 + FFN1 fused ----------------
__global__ __launch_bounds__(1024) void k_mmln(const float* __restrict__ h, const bf16* __restrict__ Bt,
                                               const float* __restrict__ lnS, const float* __restrict__ lnB,
                                               const float* __restrict__ bvec, bf16* __restrict__ outB) {
    __shared__ bf16 As[32768];
    __shared__ bf16 Bs[32768];
    __shared__ float Osh[4][16][68];
    __shared__ float sbuf[HDIM], bbuf[HDIM];
    int t = threadIdx.x, w = t >> 6, l = t & 63, lr = l & 15, lg = l >> 4;
    int ti = w & 3, s = w >> 2;
    int j0 = blockIdx.x * 64, i0 = blockIdx.y * 64;
    if (t < HDIM) sbuf[t] = lnS[t];
    else bbuf[t - HDIM] = lnB[t - HDIM];
    const bf16* Bp = Bt + (size_t)j0 * HDIM;
#pragma unroll
    for (int rnd = 0; rnd < 4; ++rnd) {
        int tt = rnd * 1024 + t;
        int ks = tt >> 8, qq = (tt >> 6) & 3, mm = (tt >> 2) & 15, gg = tt & 3;
        *(bf16x8*)(Bs + tt * 8) = *(const bf16x8*)(Bp + (size_t)(qq * 16 + mm) * HDIM + ks * 32 + gg * 8);
    }
    int row = t >> 4, ksc = t & 15;
    const float* hp = h + (size_t)(i0 + row) * HDIM + ksc * 32;
    float4 hv[8];
    float S = 0.f, Q = 0.f;
#pragma unroll
    for (int u = 0; u < 8; ++u) {
        hv[u] = *(const float4*)(hp + u * 4);
        S += hv[u].x + hv[u].y + hv[u].z + hv[u].w;
        Q += hv[u].x * hv[u].x + hv[u].y * hv[u].y + hv[u].z * hv[u].z + hv[u].w * hv[u].w;
    }
#pragma unroll
    for (int m = 1; m < 16; m <<= 1) { S += __shfl_xor(S, m); Q += __shfl_xor(Q, m); }
    float mean = S * (1.f / HDIM);
    float var = Q * (1.f / HDIM) - mean * mean;
    float rr = rsqrtf(var + 1e-5f);
    float ca = rr, cc = -mean * rr;
    __syncthreads();
    {
        bf16 tmp[32];
#pragma unroll
        for (int u = 0; u < 8; ++u) {
            float vv[4] = {hv[u].x, hv[u].y, hv[u].z, hv[u].w};
#pragma unroll
            for (int c = 0; c < 4; ++c) {
                int col = ksc * 32 + u * 4 + c;
                tmp[u * 4 + c] = (bf16)(fmaf(fmaf(vv[c], ca, cc), sbuf[col], bbuf[col]));
            }
        }
        bf16* dst = As + (row >> 4) * 8192 + ksc * 512 + (row & 15) * 32;
#pragma unroll
        for (int u = 0; u < 4; ++u) *(bf16x8*)(dst + u * 8) = *(bf16x8*)&tmp[u * 8];
    }
    __syncthreads();
    const bf16* apl = As + ti * 8192 + lr * 32 + lg * 8;
    f32x4 acc[4] = {};
#pragma unroll
    for (int kk = 0; kk < 4; ++kk) {
        int ks = s * 4 + kk;
        bf16x8 a = *(const bf16x8*)(apl + ks * 512);
        const bf16* bb = Bs + ks * 2048 + lr * 32 + lg * 8;
#pragma unroll
        for (int sub = 0; sub < 4; ++sub)
            acc[sub] = __builtin_amdgcn_mfma_f32_16x16x32_bf16(a, *(const bf16x8*)(bb + sub * 512), acc[sub], 0, 0, 0);
    }
    if (s == 0) {
#pragma unroll
        for (int sub = 0; sub < 4; ++sub)
#pragma unroll
            for (int r = 0; r < 4; ++r) Osh[ti][lg * 4 + r][sub * 16 + lr] = acc[sub][r];
    }
    __syncthreads();
    if (s == 1) {
#pragma unroll
        for (int sub = 0; sub < 4; ++sub)
#pragma unroll
            for (int r = 0; r < 4; ++r) Osh[ti][lg * 4 + r][sub * 16 + lr] += acc[sub][r];
    }
    __syncthreads();
    if (s == 2) {
#pragma unroll
        for (int sub = 0; sub < 4; ++sub)
#pragma unroll
            for (int r = 0; r < 4; ++r) Osh[ti][lg * 4 + r][sub * 16 + lr] += acc[sub][r];
    }
    __syncthreads();
    if (s == 3) {
#pragma unroll
        for (int sub = 0; sub < 4; ++sub) {
#pragma unroll
            for (int r = 0; r < 4; ++r) {
                int i = i0 + ti * 16 + lg * 4 + r;
                int j = j0 + sub * 16 + lr;
                float v = gelu_f(Osh[ti][lg * 4 + r][sub * 16 + lr] + acc[sub][r] + bvec[j]);
                outB[(size_t)i * HDIM + j] = (bf16)v;
            }
        }
    }
}

// ---------------- attention: swapped-QK flash, exp2-domain softmax, K/bias prefetch ----------------
__global__ __launch_bounds__(1024) void k_attn2(const bf16* __restrict__ qf, const bf16* __restrict__ kf,
                                                const bf16* __restrict__ vf, const bf16* __restrict__ biasb,
                                                bf16* __restrict__ ob) {
    __shared__ char Pb[16 * 1024];
    __shared__ float Osh[4][64][17];
    __shared__ float Msh[4][4][16], Lsh[4][4][16];
    int t = threadIdx.x, w = t >> 6, l = t & 63, lr = l & 15, lg = l >> 4;
    int ti = w & 3, s = w >> 2;
    int bid = blockIdx.x;
    int wid = (bid & 7) * 32 + (bid >> 3);
    int i0 = (wid >> 3) * 64, hh = wid & 7;
    int irow = i0 + ti * 16;

    const bf16* qb = qf + (((size_t)(hh * 128 + (irow >> 4)) * 2) << 9) + l * 8;
    bf16x8 qy0 = *(const bf16x8*)(qb);
    bf16x8 qy1 = *(const bf16x8*)(qb + 512);

    char* pwr = Pb + w * 1024 + lr * 64;
    unsigned kx = (unsigned)(lr & 6) << 3;

    float m_run = -3e38f, l_run = 0.f;
    f32x4 oacc[4] = {};

    int jb0 = s * 512;
    const bf16* kbp = kf + (((size_t)(hh * 128 + (jb0 >> 4)) * 2) << 9) + l * 8;
    bf16x8 ka0 = *(const bf16x8*)(kbp);
    bf16x8 ka1 = *(const bf16x8*)(kbp + 512);
    bf16x8 ka2 = *(const bf16x8*)(kbp + 1024);
    bf16x8 ka3 = *(const bf16x8*)(kbp + 1536);
    const bf16* bpp = biasb + (size_t)(irow + lr) * N_NODES + jb0 + lg * 4;
    bf16x4 ba0 = *(const bf16x4*)(bpp);
    bf16x4 ba1 = *(const bf16x4*)(bpp + 16);

    for (int it = 0; it < 16; ++it) {
        int jb = s * 512 + it * 32;
        const bf16* vb = vf + (((size_t)(hh * 4) * 64 + (jb >> 5)) << 9) + l * 8;
        bf16x8 vx0 = *(const bf16x8*)(vb);
        bf16x8 vx1 = *(const bf16x8*)(vb + 32768);
        bf16x8 vx2 = *(const bf16x8*)(vb + 65536);
        bf16x8 vx3 = *(const bf16x8*)(vb + 98304);
        bf16x8 kn0, kn1, kn2, kn3;
        bf16x4 bn0, bn1;
        if (it < 15) {
            int jn = jb + 32;
            const bf16* kbn = kf + (((size_t)(hh * 128 + (jn >> 4)) * 2) << 9) + l * 8;
            kn0 = *(const bf16x8*)(kbn);
            kn1 = *(const bf16x8*)(kbn + 512);
            kn2 = *(const bf16x8*)(kbn + 1024);
            kn3 = *(const bf16x8*)(kbn + 1536);
            const bf16* bpn = biasb + (size_t)(irow + lr) * N_NODES + jn + lg * 4;
            bn0 = *(const bf16x4*)(bpn);
            bn1 = *(const bf16x4*)(bpn + 16);
        }

        f32x4 s0v = {}, s1v = {};
        __builtin_amdgcn_s_setprio(1);
        s0v = __builtin_amdgcn_mfma_f32_16x16x32_bf16(ka0, qy0, s0v, 0, 0, 0);
        s0v = __builtin_amdgcn_mfma_f32_16x16x32_bf16(ka1, qy1, s0v, 0, 0, 0);
        s1v = __builtin_amdgcn_mfma_f32_16x16x32_bf16(ka2, qy0, s1v, 0, 0, 0);
        s1v = __builtin_amdgcn_mfma_f32_16x16x32_bf16(ka3, qy1, s1v, 0, 0, 0);
        __builtin_amdgcn_s_setprio(0);

        float p0[4], p1[4];
        float mt = -3e38f;
#pragma unroll
        for (int r = 0; r < 4; ++r) {
            p0[r] = s0v[r] + (float)ba0[r];
            p1[r] = s1v[r] + (float)ba1[r];
            mt = fmaxf(mt, fmaxf(p0[r], p1[r]));
        }
        mt = fmaxf(mt, __shfl_xor(mt, 16));
        mt = fmaxf(mt, __shfl_xor(mt, 32));
        if (!__all(mt <= m_run + 11.5416f)) {
            float mn = fmaxf(m_run, mt);
            float alpha = exp2f(m_run - mn);
            l_run *= alpha;
#pragma unroll
            for (int d = 0; d < 4; ++d) oacc[d] *= alpha;
            m_run = mn;
        }
        float ps = 0.f;
        bf16x4 pk0, pk1;
#pragma unroll
        for (int r = 0; r < 4; ++r) {
            p0[r] = exp2f(p0[r] - m_run);
            p1[r] = exp2f(p1[r] - m_run);
            ps += p0[r] + p1[r];
            pk0[r] = (bf16)p0[r];
            pk1[r] = (bf16)p1[r];
        }
        ps += __shfl_xor(ps, 16);
        ps += __shfl_xor(ps, 32);
        l_run += ps;

        *(bf16x4*)(pwr + ((lg * 8) ^ kx)) = pk0;
        *(bf16x4*)(pwr + ((32 + lg * 8) ^ kx)) = pk1;
        asm volatile("s_waitcnt lgkmcnt(0)" ::: "memory");
        __builtin_amdgcn_sched_barrier(0x20);
        bf16x8 py = *(bf16x8*)(Pb + w * 1024 + lr * 64 + ((lg * 16) ^ kx));
        __builtin_amdgcn_s_setprio(1);
        oacc[0] = __builtin_amdgcn_mfma_f32_16x16x32_bf16(vx0, py, oacc[0], 0, 0, 0);
        oacc[1] = __builtin_amdgcn_mfma_f32_16x16x32_bf16(vx1, py, oacc[1], 0, 0, 0);
        oacc[2] = __builtin_amdgcn_mfma_f32_16x16x32_bf16(vx2, py, oacc[2], 0, 0, 0);
        oacc[3] = __builtin_amdgcn_mfma_f32_16x16x32_bf16(vx3, py, oacc[3], 0, 0, 0);
        __builtin_amdgcn_s_setprio(0);
        ka0 = kn0; ka1 = kn1; ka2 = kn2; ka3 = kn3;
        ba0 = bn0; ba1 = bn1;
    }

    __syncthreads();
    if (lg == 0) { Msh[ti][s][lr] = m_run; Lsh[ti][s][lr] = l_run; }
    __syncthreads();
    float m0 = Msh[ti][0][lr], m1 = Msh[ti][1][lr], m2 = Msh[ti][2][lr], m3 = Msh[ti][3][lr];
    float mtot = fmaxf(fmaxf(m0, m1), fmaxf(m2, m3));
    float l_tot = Lsh[ti][0][lr] * exp2f(m0 - mtot) + Lsh[ti][1][lr] * exp2f(m1 - mtot)
                + Lsh[ti][2][lr] * exp2f(m2 - mtot) + Lsh[ti][3][lr] * exp2f(m3 - mtot);
    float fac = exp2f(m_run - mtot);
#pragma unroll
    for (int d = 0; d < 4; ++d) oacc[d] *= fac;
    if (s == 0) {
#pragma unroll
        for (int db = 0; db < 4; ++db)
#pragma unroll
            for (int r = 0; r < 4; ++r) Osh[ti][db * 16 + lg * 4 + r][lr] = oacc[db][r];
    }
    __syncthreads();
    if (s == 1) {
#pragma unroll
        for (int db = 0; db < 4; ++db)
#pragma unroll
            for (int r = 0; r < 4; ++r) Osh[ti][db * 16 + lg * 4 + r][lr] += oacc[db][r];
    }
    __syncthreads();
    if (s == 2) {
#pragma unroll
        for (int db = 0; db < 4; ++db)
#pragma unroll
            for (int r = 0; r < 4; ++r) Osh[ti][db * 16 + lg * 4 + r][lr] += oacc[db][r];
    }
    __syncthreads();
    if (s == 3) {
        float inv = 1.f / l_tot;
#pragma unroll
        for (int db = 0; db < 4; ++db) {
            bf16x4 o4;
#pragma unroll
            for (int r = 0; r < 4; ++r)
                o4[r] = (bf16)((Osh[ti][db * 16 + lg * 4 + r][lr] + oacc[db][r]) * inv);
            *(bf16x4*)(ob + (size_t)(irow + lr) * HDIM + hh * DK + db * 16 + lg * 4) = o4;
        }
    }
}

// ---------------- final projection: MFMA, 16-row tiles, 4-way K-split ----------------
__global__ __launch_bounds__(256) void k_fout(const float* __restrict__ h, const bf16* __restrict__ Bt,
                                              const float* __restrict__ bvec, float* __restrict__ C) {
    __shared__ float Osh[16][68];
    int t = threadIdx.x, s = t >> 6, l = t & 63, lr = l & 15, lg = l >> 4;
    int i0 = blockIdx.x * 16;
    const float* ap = h + (size_t)(i0 + lr) * HDIM + s * 128 + lg * 8;
    f32x4 acc[4] = {};
#pragma unroll
    for (int kk = 0; kk < 4; ++kk) {
        float4 f0 = *(const float4*)(ap + kk * 32);
        float4 f1 = *(const float4*)(ap + kk * 32 + 4);
        bf16x8 a;
        a[0] = (bf16)f0.x; a[1] = (bf16)f0.y; a[2] = (bf16)f0.z; a[3] = (bf16)f0.w;
        a[4] = (bf16)f1.x; a[5] = (bf16)f1.y; a[6] = (bf16)f1.z; a[7] = (bf16)f1.w;
#pragma unroll
        for (int sub = 0; sub < 4; ++sub) {
            bf16x8 b = *(const bf16x8*)(Bt + (size_t)(sub * 16 + lr) * HDIM + s * 128 + kk * 32 + lg * 8);
            acc[sub] = __builtin_amdgcn_mfma_f32_16x16x32_bf16(a, b, acc[sub], 0, 0, 0);
        }
    }
    if (s == 0) {
#pragma unroll
        for (int sub = 0; sub < 4; ++sub)
#pragma unroll
            for (int r = 0; r < 4; ++r) Osh[lg * 4 + r][sub * 16 + lr] = acc[sub][r];
    }
    __syncthreads();
    if (s == 1) {
#pragma unroll
        for (int sub = 0; sub < 4; ++sub)
#pragma unroll
            for (int r = 0; r < 4; ++r) Osh[lg * 4 + r][sub * 16 + lr] += acc[sub][r];
    }
    __syncthreads();
    if (s == 2) {
#pragma unroll
        for (int sub = 0; sub < 4; ++sub)
#pragma unroll
            for (int r = 0; r < 4; ++r) Osh[lg * 4 + r][sub * 16 + lr] += acc[sub][r];
    }
    __syncthreads();
    if (s == 3) {
#pragma unroll
        for (int sub = 0; sub < 4; ++sub) {
#pragma unroll
            for (int r = 0; r < 4; ++r) {
                int i = i0 + lg * 4 + r;
                int j = sub * 16 + lr;
                C[(size_t)i * ODIM + j] = Osh[lg * 4 + r][sub * 16 + lr] + acc[sub][r] + bvec[j];
            }
        }
    }
}

extern "C" void kernel_launch(void* const* d_in, const int* in_sizes, int n_in,
                              void* d_out, int out_size, void* d_ws, size_t ws_size,
                              hipStream_t stream) {
    const float* x      = (const float*)d_in[0];
    const int*   ei     = (const int*)d_in[1];
    const float* eattr  = (const float*)d_in[2];
    const int*   epaths = (const int*)d_in[4];
    const float* Wn     = (const float*)d_in[5];
    const float* bn     = (const float*)d_in[6];
    const float* We     = (const float*)d_in[7];
    const float* be     = (const float*)d_in[8];
    const float* zin    = (const float*)d_in[9];
    const float* zout   = (const float*)d_in[10];
    const float* bsp    = (const float*)d_in[11];
    const float* ev     = (const float*)d_in[12];
    const float* ln1s   = (const float*)d_in[13];
    const float* ln1b   = (const float*)d_in[14];
    const float* Wq     = (const float*)d_in[15];
    const float* bq     = (const float*)d_in[16];
    const float* Wk     = (const float*)d_in[17];
    const float* bk     = (const float*)d_in[18];
    const float* Wv     = (const float*)d_in[19];
    const float* bv     = (const float*)d_in[20];
    const float* Wo     = (const float*)d_in[21];
    const float* bo     = (const float*)d_in[22];
    const float* ln2s   = (const float*)d_in[23];
    const float* ln2b   = (const float*)d_in[24];
    const float* W1     = (const float*)d_in[25];
    const float* b1     = (const float*)d_in[26];
    const float* W2     = (const float*)d_in[27];
    const float* b2     = (const float*)d_in[28];
    const float* Wout   = (const float*)d_in[29];
    const float* bout   = (const float*)d_in[30];

    char* base = (char*)d_ws;
    size_t off = 0;
    auto alloc = [&](size_t bytes) { char* p = base + off; off = (off + bytes + 255) & ~(size_t)255; return p; };
    bf16*  bias   = (bf16*)alloc((size_t)N_NODES * N_NODES * 2);
    float* h      = (float*)alloc((size_t)N_NODES * HDIM * 4);
    bf16*  wT     = (bf16*)alloc((size_t)LPATH * NEDGE * 2);
    int*   deg    = (int*)alloc(2 * N_NODES * 4);
    bf16*  WnT    = (bf16*)alloc((size_t)HDIM * FDIM * 2);
    bf16*  WoutT  = (bf16*)alloc((size_t)ODIM * HDIM * 2);
    bf16*  Wt     = (bf16*)alloc((size_t)NLAYER * 6 * HDIM * HDIM * 2);
    bf16*  qfb    = (bf16*)alloc((size_t)NHEAD * 128 * 2 * 512 * 2);
    bf16*  kfb    = (bf16*)alloc((size_t)NHEAD * 128 * 2 * 512 * 2);
    bf16*  vfb    = (bf16*)alloc((size_t)NHEAD * 4 * 64 * 512 * 2);
    bf16*  ob_bf  = (bf16*)alloc((size_t)N_NODES * HDIM * 2);
    bf16*  t1_bf  = (bf16*)alloc((size_t)N_NODES * HDIM * 2);
    int* din = deg;
    int* dout = deg + N_NODES;

    hipMemsetAsync(deg, 0, 2 * N_NODES * sizeof(int), stream);

    k_prep<<<1920, 256, 0, stream>>>(eattr, We, be, ev, ei, din, dout, wT,
                                     Wq, Wk, Wv, Wo, W1, W2, Wn, Wout, Wt, WnT, WoutT);
    k_bias3<<<512, 1024, 0, stream>>>(epaths, wT, bsp, bias);
    k_nmm<<<dim3(8, 32), 256, 0, stream>>>(x, WnT, bn, zin, zout, din, dout, h);

    dim3 gqkv(48, 32);
    dim3 gmm(8, 32);

    for (int lay = 0; lay < NLAYER; ++lay) {
        const bf16* Wt_l = Wt + (size_t)lay * 6 * HDIM * HDIM;
        size_t bOff = (size_t)lay * HDIM;
        k_lnqkv<<<gqkv, 256, 0, stream>>>(h, Wt_l, ln1s + bOff, ln1b + bOff,
                                          bq + bOff, bk + bOff, bv + bOff, qfb, kfb, vfb);
        k_attn2<<<256, 1024, 0, stream>>>(qfb, kfb, vfb, bias, ob_bf);
        k_mm<<<gmm, 1024, 0, stream>>>(ob_bf, Wt_l + (size_t)3 * HDIM * HDIM, bo + bOff, h, h, nullptr, FL_RES | FL_OUTF);
        k_mmln<<<gmm, 1024, 0, stream>>>(h, Wt_l + (size_t)4 * HDIM * HDIM, ln2s + bOff, ln2b + bOff, b1 + bOff, t1_bf);
        k_mm<<<gmm, 1024, 0, stream>>>(t1_bf, Wt_l + (size_t)5 * HDIM * HDIM, b2 + bOff, h, h, nullptr, FL_RES | FL_OUTF);
    }
    k_fout<<<128, 256, 0, stream>>>(h, WoutT, bout, (float*)d_out);
}

// Round 15
// 455.064 us; speedup vs baseline: 1.4042x; 1.4042x over previous
//
#include <hip/hip_runtime.h>
#include <hip/hip_bf16.h>
#include <math.h>

#define N_NODES 2048
#define NEDGE   65536
#define FDIM    128
#define HDIM    512
#define EFD     16
#define EDD     64
#define LPATH   5
#define NLAYER  4
#define NHEAD   8
#define DK      64
#define ODIM    64
#define MAXDEG  64
#define PTOT    4194304
#define LOG2E   1.4426950408889634f

typedef __bf16 bf16;
typedef bf16 bf16x8 __attribute__((ext_vector_type(8)));
typedef bf16 bf16x4 __attribute__((ext_vector_type(4)));
typedef float f32x4 __attribute__((ext_vector_type(4)));
typedef unsigned short u16;

// ---------------- fused prep: blocks [0,256) = edge weights + degrees; [256,1920) = weight transposes ----------------
__global__ __launch_bounds__(256) void k_prep(const float* __restrict__ ea, const float* __restrict__ We,
                                              const float* __restrict__ be, const float* __restrict__ ev,
                                              const int* __restrict__ ei, int* __restrict__ din,
                                              int* __restrict__ dout, bf16* __restrict__ wT,
                                              const float* __restrict__ Wq, const float* __restrict__ Wk,
                                              const float* __restrict__ Wv, const float* __restrict__ Wo,
                                              const float* __restrict__ W1, const float* __restrict__ W2,
                                              const float* __restrict__ Wn, const float* __restrict__ Wout,
                                              bf16* __restrict__ Wt, bf16* __restrict__ WnT,
                                              bf16* __restrict__ WoutT) {
    __shared__ float sM[80];
    __shared__ float sc[8];
    __shared__ float Ls[64][68];
    int t = threadIdx.x;
    int bx = blockIdx.x;
    if (bx < 256) {
        if (t < 80) {
            int i = t / 5, j = t % 5;
            float acc = 0.f;
            for (int k = 0; k < EDD; ++k) acc += We[i * EDD + k] * ev[j * EDD + k];
            sM[t] = acc;
        } else if (t >= 128 && t < 128 + LPATH) {
            int j = t - 128;
            float acc = 0.f;
            for (int k = 0; k < EDD; ++k) acc += be[k] * ev[j * EDD + k];
            sc[j] = acc;
        }
        int e = bx * 256 + t;
        atomicAdd(&dout[ei[e]], 1);
        atomicAdd(&din[ei[NEDGE + e]], 1);
        __syncthreads();
        const float4* p = (const float4*)(ea + (size_t)e * EFD);
        float4 a0 = p[0], a1 = p[1], a2 = p[2], a3 = p[3];
        float a[16] = {a0.x, a0.y, a0.z, a0.w, a1.x, a1.y, a1.z, a1.w,
                       a2.x, a2.y, a2.z, a2.w, a3.x, a3.y, a3.z, a3.w};
        float out[LPATH];
#pragma unroll
        for (int j = 0; j < LPATH; ++j) out[j] = sc[j];
#pragma unroll
        for (int i = 0; i < 16; ++i)
#pragma unroll
            for (int j = 0; j < LPATH; ++j) out[j] += a[i] * sM[i * LPATH + j];
#pragma unroll
        for (int j = 0; j < LPATH; ++j) wT[(size_t)j * NEDGE + e] = (bf16)out[j];
        return;
    }
    int m = (bx - 256) >> 6;
    int q = (bx - 256) & 63;
    int rr = t >> 4, cc = t & 15;
    int nl = t >> 2, kc = t & 3;
    if (m < 24) {
        int lay = m / 6, type = m % 6;
        const float* src = type == 0 ? Wq : type == 1 ? Wk : type == 2 ? Wv : type == 3 ? Wo : type == 4 ? W1 : W2;
        src += (size_t)lay * (HDIM * HDIM);
        int tk = q >> 3, tn = q & 7;
#pragma unroll
        for (int u = 0; u < 4; ++u) {
            float4 v = *(const float4*)(src + (size_t)(tk * 64 + rr + 16 * u) * HDIM + tn * 64 + cc * 4);
            *(float4*)&Ls[rr + 16 * u][cc * 4] = v;
        }
        __syncthreads();
        bf16 tmp[16];
#pragma unroll
        for (int u = 0; u < 16; ++u) tmp[u] = (bf16)Ls[kc * 16 + u][nl];
        bf16* dst = Wt + (size_t)m * (HDIM * HDIM) + (size_t)(tn * 64 + nl) * HDIM + tk * 64 + kc * 16;
        *(bf16x8*)(dst) = *(bf16x8*)&tmp[0];
        *(bf16x8*)(dst + 8) = *(bf16x8*)&tmp[8];
    } else if (m == 24) {
        if (q >= 16) return;
        int tk = q >> 3, tn = q & 7;
#pragma unroll
        for (int u = 0; u < 4; ++u) {
            float4 v = *(const float4*)(Wn + (size_t)(tk * 64 + rr + 16 * u) * HDIM + tn * 64 + cc * 4);
            *(float4*)&Ls[rr + 16 * u][cc * 4] = v;
        }
        __syncthreads();
        bf16 tmp[16];
#pragma unroll
        for (int u = 0; u < 16; ++u) tmp[u] = (bf16)Ls[kc * 16 + u][nl];
        bf16* dst = WnT + (size_t)(tn * 64 + nl) * FDIM + tk * 64 + kc * 16;
        *(bf16x8*)dst = *(bf16x8*)&tmp[0];
        *(bf16x8*)(dst + 8) = *(bf16x8*)&tmp[8];
    } else {
        if (q >= 8) return;
        int tk = q;
#pragma unroll
        for (int u = 0; u < 4; ++u) {
            float4 v = *(const float4*)(Wout + (size_t)(tk * 64 + rr + 16 * u) * ODIM + cc * 4);
            *(float4*)&Ls[rr + 16 * u][cc * 4] = v;
        }
        __syncthreads();
        bf16 tmp[16];
#pragma unroll
        for (int u = 0; u < 16; ++u) tmp[u] = (bf16)Ls[kc * 16 + u][nl];
        bf16* dst = WoutT + (size_t)nl * HDIM + tk * 64 + kc * 16;
        *(bf16x8*)dst = *(bf16x8*)&tmp[0];
        *(bf16x8*)(dst + 8) = *(bf16x8*)&tmp[8];
    }
}

// ---------------- bias: r8 structure (single 8192-pair chunk, spill-free). Output bias * LOG2E ----------------
__global__ __launch_bounds__(1024) void k_bias3(const int* __restrict__ ep, const bf16* __restrict__ wT,
                                                const float* __restrict__ bsp, bf16* __restrict__ bias) {
    __shared__ char lds[163840];
    int t = threadIdx.x;
    size_t basep = (size_t)blockIdx.x * 8192;
    int* ish = (int*)lds;
    const int4* src = (const int4*)(ep + basep * 5);
#pragma unroll
    for (int u = 0; u < 10; ++u) ((int4*)ish)[t + 1024 * u] = src[t + 1024 * u];
    __syncthreads();
    unsigned pa[8], pb[8], pc[8];
#pragma unroll
    for (int r = 0; r < 8; ++r) {
        int p5 = (r * 1024 + t) * 5;
        int e0 = ish[p5], e1 = ish[p5 + 1], e2 = ish[p5 + 2], e3 = ish[p5 + 3], e4 = ish[p5 + 4];
        unsigned mk = (unsigned)(e0 >= 0) | ((unsigned)(e1 >= 0) << 1) | ((unsigned)(e2 >= 0) << 2)
                    | ((unsigned)(e3 >= 0) << 3) | ((unsigned)(e4 >= 0) << 4);
        pa[r] = ((unsigned)e0 & 0xFFFFu) | ((unsigned)e1 << 16);
        pb[r] = ((unsigned)e2 & 0xFFFFu) | ((unsigned)e3 << 16);
        pc[r] = ((unsigned)e4 & 0xFFFFu) | (mk << 16);
    }
    bf16* wsl = (bf16*)lds;
    float csum[8] = {};
#pragma unroll
    for (int l = 0; l < LPATH; ++l) {
        __syncthreads();
#pragma unroll
        for (int u = 0; u < 4; ++u) {
            int o = u * 16384 + t * 16;
            *(bf16x8*)&wsl[o]     = *(const bf16x8*)&wT[(size_t)l * NEDGE + o];
            *(bf16x8*)&wsl[o + 8] = *(const bf16x8*)&wT[(size_t)l * NEDGE + o + 8];
        }
        __syncthreads();
#pragma unroll
        for (int r = 0; r < 8; ++r) {
            unsigned ix = (l == 0) ? (pa[r] & 0xFFFFu) : (l == 1) ? (pa[r] >> 16)
                        : (l == 2) ? (pb[r] & 0xFFFFu) : (l == 3) ? (pb[r] >> 16) : (pc[r] & 0xFFFFu);
            float v = (float)wsl[ix];
            csum[r] += ((pc[r] >> (16 + l)) & 1u) ? v : 0.f;
        }
    }
#pragma unroll
    for (int r = 0; r < 8; ++r) {
        int cnt = __popc((int)((pc[r] >> 16) & 0x1Fu));
        float b = cnt ? (bsp[cnt - 1] + csum[r] / (float)cnt) * LOG2E : 0.f;
        bias[basep + r * 1024 + t] = (bf16)b;
    }
}

// ---------------- layernorm (LN1): wave-per-row, shuffle-only ----------------
__global__ __launch_bounds__(256) void k_ln(const float* __restrict__ h, const float* __restrict__ sc,
                                            const float* __restrict__ bi, bf16* __restrict__ y) {
    int t = threadIdx.x, w = t >> 6, l = t & 63;
    int row = blockIdx.x * 4 + w;
    const float* hp = h + (size_t)row * HDIM + l * 8;
    float4 a = *(const float4*)hp;
    float4 b = *(const float4*)(hp + 4);
    float s = a.x + a.y + a.z + a.w + b.x + b.y + b.z + b.w;
    float q = a.x * a.x + a.y * a.y + a.z * a.z + a.w * a.w
            + b.x * b.x + b.y * b.y + b.z * b.z + b.w * b.w;
#pragma unroll
    for (int m = 1; m < 64; m <<= 1) { s += __shfl_xor(s, m); q += __shfl_xor(q, m); }
    float mean = s * (1.f / HDIM);
    float var = q * (1.f / HDIM) - mean * mean;
    float r = rsqrtf(var + 1e-5f);
    float4 s0 = *(const float4*)(sc + l * 8), s1 = *(const float4*)(sc + l * 8 + 4);
    float4 b0 = *(const float4*)(bi + l * 8), b1 = *(const float4*)(bi + l * 8 + 4);
    float va[8] = {a.x, a.y, a.z, a.w, b.x, b.y, b.z, b.w};
    float ss[8] = {s0.x, s0.y, s0.z, s0.w, s1.x, s1.y, s1.z, s1.w};
    float bb[8] = {b0.x, b0.y, b0.z, b0.w, b1.x, b1.y, b1.z, b1.w};
    bf16x8 o;
#pragma unroll
    for (int c = 0; c < 8; ++c) o[c] = (bf16)((va[c] - mean) * r * ss[c] + bb[c]);
    *(bf16x8*)(y + (size_t)row * HDIM + l * 8) = o;
}

// node projection as MFMA GEMM (K=128, f32 x inline-cast) + degree-embedding epilogue
__global__ __launch_bounds__(256) void k_nmm(const float* __restrict__ x, const bf16* __restrict__ Bt,
                                             const float* __restrict__ bn, const float* __restrict__ zin,
                                             const float* __restrict__ zout, const int* __restrict__ din,
                                             const int* __restrict__ dout, float* __restrict__ h) {
    __shared__ bf16 Bs[8192];
    int t = threadIdx.x, w = t >> 6, l = t & 63, lr = l & 15, lg = l >> 4;
    int j0 = blockIdx.x * 64, i0 = blockIdx.y * 64;
    const bf16* Bp = Bt + (size_t)j0 * FDIM;
#pragma unroll
    for (int rnd = 0; rnd < 4; ++rnd) {
        int tt = rnd * 256 + t;
        int ks = tt >> 8, qq = (tt >> 6) & 3, mm = (tt >> 2) & 15, gg = tt & 3;
        *(bf16x8*)(Bs + tt * 8) = *(const bf16x8*)(Bp + (size_t)(qq * 16 + mm) * FDIM + ks * 32 + gg * 8);
    }
    __syncthreads();
    const float* ap = x + (size_t)(i0 + w * 16 + lr) * FDIM + 8 * lg;
    f32x4 acc[4] = {};
#pragma unroll
    for (int ks = 0; ks < 4; ++ks) {
        float4 f0 = *(const float4*)(ap + ks * 32);
        float4 f1 = *(const float4*)(ap + ks * 32 + 4);
        bf16x8 a;
        a[0] = (bf16)f0.x; a[1] = (bf16)f0.y; a[2] = (bf16)f0.z; a[3] = (bf16)f0.w;
        a[4] = (bf16)f1.x; a[5] = (bf16)f1.y; a[6] = (bf16)f1.z; a[7] = (bf16)f1.w;
        const bf16* bb = Bs + ks * 2048 + lr * 32 + lg * 8;
#pragma unroll
        for (int sub = 0; sub < 4; ++sub)
            acc[sub] = __builtin_amdgcn_mfma_f32_16x16x32_bf16(a, *(const bf16x8*)(bb + sub * 512), acc[sub], 0, 0, 0);
    }
#pragma unroll
    for (int r = 0; r < 4; ++r) {
        int i = i0 + w * 16 + lg * 4 + r;
        int di = min(din[i], MAXDEG - 1), dz = min(dout[i], MAXDEG - 1);
#pragma unroll
        for (int sub = 0; sub < 4; ++sub) {
            int j = j0 + sub * 16 + lr;
            h[(size_t)i * HDIM + j] = acc[sub][r] + bn[j] + zin[(size_t)di * HDIM + j] + zout[(size_t)dz * HDIM + j];
        }
    }
}

// ---------------- fused QKV GEMM -> frag-contiguous q/k/v layouts ----------------
// q pre-scaled by 0.125*LOG2E (attn softmax in exp2 domain)
__global__ __launch_bounds__(256) void k_qkv(const bf16* __restrict__ A, const bf16* __restrict__ Wt_l,
                                             const float* __restrict__ bq, const float* __restrict__ bk,
                                             const float* __restrict__ bv, bf16* __restrict__ qf,
                                             bf16* __restrict__ kf, bf16* __restrict__ vf) {
    __shared__ bf16 Bs[16384];
    int t = threadIdx.x, w = t >> 6, l = t & 63, lr = l & 15, lg = l >> 4;
    int j0 = blockIdx.x * 32, i0 = blockIdx.y * 64;
    int type = j0 >> 9, n0 = j0 & 511;
    const bf16* Bp = Wt_l + (size_t)type * (HDIM * HDIM) + (size_t)n0 * HDIM;
#pragma unroll
    for (int rnd = 0; rnd < 8; ++rnd) {
        int tt = rnd * 256 + t;
        int ks = tt >> 7, qq = (tt >> 6) & 1, mm = (tt >> 2) & 15, gg = tt & 3;
        bf16x8 v = *(const bf16x8*)(Bp + (size_t)(qq * 16 + mm) * HDIM + ks * 32 + gg * 8);
        *(bf16x8*)(Bs + tt * 8) = v;
    }
    __syncthreads();
    const bf16* ap = A + (size_t)(i0 + w * 16 + lr) * HDIM + 8 * lg;
    const float* bvec = (type == 0 ? bq : type == 1 ? bk : bv);
    f32x4 acc[2] = {};
#pragma unroll 4
    for (int ks = 0; ks < 16; ++ks) {
        bf16x8 a  = *(const bf16x8*)(ap + ks * 32);
        const bf16* bb = Bs + ks * 1024 + lr * 32 + lg * 8;
        bf16x8 b0 = *(const bf16x8*)(bb);
        bf16x8 b1 = *(const bf16x8*)(bb + 512);
        acc[0] = __builtin_amdgcn_mfma_f32_16x16x32_bf16(a, b0, acc[0], 0, 0, 0);
        acc[1] = __builtin_amdgcn_mfma_f32_16x16x32_bf16(a, b1, acc[1], 0, 0, 0);
    }
    int h = n0 >> 6;
    if (type < 2) {
        bf16* dst = (type == 0 ? qf : kf);
        int hf = (n0 & 32) >> 5;
        float sc = (type == 0 ? 0.125f * LOG2E : 1.0f);
#pragma unroll
        for (int sub = 0; sub < 2; ++sub) {
#pragma unroll
            for (int r = 0; r < 4; ++r) {
                int i = i0 + w * 16 + lg * 4 + r;
                float v = (acc[sub][r] + bvec[n0 + sub * 16 + lr]) * sc;
                int lgp = sub * 2 + (lr >> 3);
                size_t off = (((size_t)(h * 128 + (i >> 4)) * 2 + hf) << 9) + lgp * 128 + (lg * 4 + r) * 8 + (lr & 7);
                dst[off] = (bf16)v;
            }
        }
    } else {
#pragma unroll
        for (int sub = 0; sub < 2; ++sub) {
#pragma unroll
            for (int r = 0; r < 4; ++r) {
                int node = i0 + w * 16 + lg * 4 + r;
                int dd = (n0 & 63) + sub * 16 + lr;
                float v = acc[sub][r] + bvec[n0 + sub * 16 + lr];
                size_t off = (((size_t)(h * 4 + (dd >> 4)) * 64 + (node >> 5)) << 9)
                           + ((node >> 3) & 3) * 128 + (dd & 15) * 8 + (node & 7);
                vf[off] = (bf16)v;
            }
        }
    }
}

// ---------------- generic bf16 MFMA GEMM, BN=64, 16 waves, 4-way K-split ----------------
#define FL_RES   1
#define FL_GELU  2
#define FL_OUTF  4

__device__ inline float gelu_f(float x) {
    float x3 = x * x * x;
    float u = 0.7978845608028654f * (x + 0.044715f * x3);
    return 0.5f * x * (1.f + tanhf(u));
}

__global__ __launch_bounds__(1024) void k_mm(const bf16* __restrict__ A, const bf16* __restrict__ Bt,
                                             const float* __restrict__ bvec, const float* __restrict__ res,
                                             float* __restrict__ outF, bf16* __restrict__ outB, int flags) {
    __shared__ bf16 Bs[32768];
    __shared__ float Osh[4][16][68];
    int t = threadIdx.x, w = t >> 6, l = t & 63, lr = l & 15, lg = l >> 4;
    int ti = w & 3, s = w >> 2;
    int j0 = blockIdx.x * 64, i0 = blockIdx.y * 64;
    const bf16* Bp = Bt + (size_t)j0 * HDIM;
#pragma unroll
    for (int rnd = 0; rnd < 4; ++rnd) {
        int tt = rnd * 1024 + t;
        int ks = tt >> 8, qq = (tt >> 6) & 3, mm = (tt >> 2) & 15, gg = tt & 3;
        bf16x8 v = *(const bf16x8*)(Bp + (size_t)(qq * 16 + mm) * HDIM + ks * 32 + gg * 8);
        *(bf16x8*)(Bs + tt * 8) = v;
    }
    __syncthreads();
    const bf16* ap = A + (size_t)(i0 + ti * 16 + lr) * HDIM + 8 * lg;
    f32x4 acc[4] = {};
#pragma unroll
    for (int kk = 0; kk < 4; ++kk) {
        int ks = s * 4 + kk;
        bf16x8 a = *(const bf16x8*)(ap + ks * 32);
        const bf16* bb = Bs + ks * 2048 + lr * 32 + lg * 8;
#pragma unroll
        for (int sub = 0; sub < 4; ++sub) {
            bf16x8 b = *(const bf16x8*)(bb + sub * 512);
            acc[sub] = __builtin_amdgcn_mfma_f32_16x16x32_bf16(a, b, acc[sub], 0, 0, 0);
        }
    }
    if (s == 0) {
#pragma unroll
        for (int sub = 0; sub < 4; ++sub)
#pragma unroll
            for (int r = 0; r < 4; ++r) Osh[ti][lg * 4 + r][sub * 16 + lr] = acc[sub][r];
    }
    __syncthreads();
    if (s == 1) {
#pragma unroll
        for (int sub = 0; sub < 4; ++sub)
#pragma unroll
            for (int r = 0; r < 4; ++r) Osh[ti][lg * 4 + r][sub * 16 + lr] += acc[sub][r];
    }
    __syncthreads();
    if (s == 2) {
#pragma unroll
        for (int sub = 0; sub < 4; ++sub)
#pragma unroll
            for (int r = 0; r < 4; ++r) Osh[ti][lg * 4 + r][sub * 16 + lr] += acc[sub][r];
    }
    __syncthreads();
    if (s == 3) {
#pragma unroll
        for (int sub = 0; sub < 4; ++sub) {
#pragma unroll
            for (int r = 0; r < 4; ++r) {
                int i = i0 + ti * 16 + lg * 4 + r;
                int j = j0 + sub * 16 + lr;
                float v = Osh[ti][lg * 4 + r][sub * 16 + lr] + acc[sub][r] + bvec[j];
                if (flags & FL_RES) v += res[(size_t)i * HDIM + j];
                if (flags & FL_GELU) v = gelu_f(v);
                if (flags & FL_OUTF) outF[(size_t)i * HDIM + j] = v;
                else outB[(size_t)i * HDIM + j] = (bf16)v;
            }
        }
    }
}

// ---------------- LN2 + FFN1 fused ----------------
__global__ __launch_bounds__(1024) void k_mmln(const float* __restrict__ h, const bf16* __restrict__ Bt,
                                               const float* __restrict__ lnS, const float* __restrict__ lnB,
                                               const float* __restrict__ bvec, bf16* __restrict__ outB) {
    __shared__ bf16 As[32768];
    __shared__ bf16 Bs[32768];
    __shared__ float Osh[4][16][68];
    __shared__ float sbuf[HDIM], bbuf[HDIM];
    int t = threadIdx.x, w = t >> 6, l = t & 63, lr = l & 15, lg = l >> 4;
    int ti = w & 3, s = w >> 2;
    int j0 = blockIdx.x * 64, i0 = blockIdx.y * 64;
    if (t < HDIM) sbuf[t] = lnS[t];
    else bbuf[t - HDIM] = lnB[t - HDIM];
    const bf16* Bp = Bt + (size_t)j0 * HDIM;
#pragma unroll
    for (int rnd = 0; rnd < 4; ++rnd) {
        int tt = rnd * 1024 + t;
        int ks = tt >> 8, qq = (tt >> 6) & 3, mm = (tt >> 2) & 15, gg = tt & 3;
        *(bf16x8*)(Bs + tt * 8) = *(const bf16x8*)(Bp + (size_t)(qq * 16 + mm) * HDIM + ks * 32 + gg * 8);
    }
    int row = t >> 4, ksc = t & 15;
    const float* hp = h + (size_t)(i0 + row) * HDIM + ksc * 32;
    float4 hv[8];
    float S = 0.f, Q = 0.f;
#pragma unroll
    for (int u = 0; u < 8; ++u) {
        hv[u] = *(const float4*)(hp + u * 4);
        S += hv[u].x + hv[u].y + hv[u].z + hv[u].w;
        Q += hv[u].x * hv[u].x + hv[u].y * hv[u].y + hv[u].z * hv[u].z + hv[u].w * hv[u].w;
    }
#pragma unroll
    for (int m = 1; m < 16; m <<= 1) { S += __shfl_xor(S, m); Q += __shfl_xor(Q, m); }
    float mean = S * (1.f / HDIM);
    float var = Q * (1.f / HDIM) - mean * mean;
    float rr = rsqrtf(var + 1e-5f);
    float ca = rr, cc = -mean * rr;
    __syncthreads();
    {
        bf16 tmp[32];
#pragma unroll
        for (int u = 0; u < 8; ++u) {
            float vv[4] = {hv[u].x, hv[u].y, hv[u].z, hv[u].w};
#pragma unroll
            for (int c = 0; c < 4; ++c) {
                int col = ksc * 32 + u * 4 + c;
                tmp[u * 4 + c] = (bf16)(fmaf(fmaf(vv[c], ca, cc), sbuf[col], bbuf[col]));
            }
        }
        bf16* dst = As + (row >> 4) * 8192 + ksc * 512 + (row & 15) * 32;
#pragma unroll
        for (int u = 0; u < 4; ++u) *(bf16x8*)(dst + u * 8) = *(bf16x8*)&tmp[u * 8];
    }
    __syncthreads();
    const bf16* apl = As + ti * 8192 + lr * 32 + lg * 8;
    f32x4 acc[4] = {};
#pragma unroll
    for (int kk = 0; kk < 4; ++kk) {
        int ks = s * 4 + kk;
        bf16x8 a = *(const bf16x8*)(apl + ks * 512);
        const bf16* bb = Bs + ks * 2048 + lr * 32 + lg * 8;
#pragma unroll
        for (int sub = 0; sub < 4; ++sub)
            acc[sub] = __builtin_amdgcn_mfma_f32_16x16x32_bf16(a, *(const bf16x8*)(bb + sub * 512), acc[sub], 0, 0, 0);
    }
    if (s == 0) {
#pragma unroll
        for (int sub = 0; sub < 4; ++sub)
#pragma unroll
            for (int r = 0; r < 4; ++r) Osh[ti][lg * 4 + r][sub * 16 + lr] = acc[sub][r];
    }
    __syncthreads();
    if (s == 1) {
#pragma unroll
        for (int sub = 0; sub < 4; ++sub)
#pragma unroll
            for (int r = 0; r < 4; ++r) Osh[ti][lg * 4 + r][sub * 16 + lr] += acc[sub][r];
    }
    __syncthreads();
    if (s == 2) {
#pragma unroll
        for (int sub = 0; sub < 4; ++sub)
#pragma unroll
            for (int r = 0; r < 4; ++r) Osh[ti][lg * 4 + r][sub * 16 + lr] += acc[sub][r];
    }
    __syncthreads();
    if (s == 3) {
#pragma unroll
        for (int sub = 0; sub < 4; ++sub) {
#pragma unroll
            for (int r = 0; r < 4; ++r) {
                int i = i0 + ti * 16 + lg * 4 + r;
                int j = j0 + sub * 16 + lr;
                float v = gelu_f(Osh[ti][lg * 4 + r][sub * 16 + lr] + acc[sub][r] + bvec[j]);
                outB[(size_t)i * HDIM + j] = (bf16)v;
            }
        }
    }
}

// ---------------- attention: swapped-QK flash, exp2-domain softmax, K/bias prefetch ----------------
__global__ __launch_bounds__(1024) void k_attn2(const bf16* __restrict__ qf, const bf16* __restrict__ kf,
                                                const bf16* __restrict__ vf, const bf16* __restrict__ biasb,
                                                bf16* __restrict__ ob) {
    __shared__ char Pb[16 * 1024];
    __shared__ float Osh[4][64][17];
    __shared__ float Msh[4][4][16], Lsh[4][4][16];
    int t = threadIdx.x, w = t >> 6, l = t & 63, lr = l & 15, lg = l >> 4;
    int ti = w & 3, s = w >> 2;
    int bid = blockIdx.x;
    int wid = (bid & 7) * 32 + (bid >> 3);
    int i0 = (wid >> 3) * 64, hh = wid & 7;
    int irow = i0 + ti * 16;

    const bf16* qb = qf + (((size_t)(hh * 128 + (irow >> 4)) * 2) << 9) + l * 8;
    bf16x8 qy0 = *(const bf16x8*)(qb);
    bf16x8 qy1 = *(const bf16x8*)(qb + 512);

    char* pwr = Pb + w * 1024 + lr * 64;
    unsigned kx = (unsigned)(lr & 6) << 3;

    float m_run = -3e38f, l_run = 0.f;
    f32x4 oacc[4] = {};

    int jb0 = s * 512;
    const bf16* kbp = kf + (((size_t)(hh * 128 + (jb0 >> 4)) * 2) << 9) + l * 8;
    bf16x8 ka0 = *(const bf16x8*)(kbp);
    bf16x8 ka1 = *(const bf16x8*)(kbp + 512);
    bf16x8 ka2 = *(const bf16x8*)(kbp + 1024);
    bf16x8 ka3 = *(const bf16x8*)(kbp + 1536);
    const bf16* bpp = biasb + (size_t)(irow + lr) * N_NODES + jb0 + lg * 4;
    bf16x4 ba0 = *(const bf16x4*)(bpp);
    bf16x4 ba1 = *(const bf16x4*)(bpp + 16);

    for (int it = 0; it < 16; ++it) {
        int jb = s * 512 + it * 32;
        const bf16* vb = vf + (((size_t)(hh * 4) * 64 + (jb >> 5)) << 9) + l * 8;
        bf16x8 vx0 = *(const bf16x8*)(vb);
        bf16x8 vx1 = *(const bf16x8*)(vb + 32768);
        bf16x8 vx2 = *(const bf16x8*)(vb + 65536);
        bf16x8 vx3 = *(const bf16x8*)(vb + 98304);
        bf16x8 kn0, kn1, kn2, kn3;
        bf16x4 bn0, bn1;
        if (it < 15) {
            int jn = jb + 32;
            const bf16* kbn = kf + (((size_t)(hh * 128 + (jn >> 4)) * 2) << 9) + l * 8;
            kn0 = *(const bf16x8*)(kbn);
            kn1 = *(const bf16x8*)(kbn + 512);
            kn2 = *(const bf16x8*)(kbn + 1024);
            kn3 = *(const bf16x8*)(kbn + 1536);
            const bf16* bpn = biasb + (size_t)(irow + lr) * N_NODES + jn + lg * 4;
            bn0 = *(const bf16x4*)(bpn);
            bn1 = *(const bf16x4*)(bpn + 16);
        }

        f32x4 s0v = {}, s1v = {};
        __builtin_amdgcn_s_setprio(1);
        s0v = __builtin_amdgcn_mfma_f32_16x16x32_bf16(ka0, qy0, s0v, 0, 0, 0);
        s0v = __builtin_amdgcn_mfma_f32_16x16x32_bf16(ka1, qy1, s0v, 0, 0, 0);
        s1v = __builtin_amdgcn_mfma_f32_16x16x32_bf16(ka2, qy0, s1v, 0, 0, 0);
        s1v = __builtin_amdgcn_mfma_f32_16x16x32_bf16(ka3, qy1, s1v, 0, 0, 0);
        __builtin_amdgcn_s_setprio(0);

        float p0[4], p1[4];
        float mt = -3e38f;
#pragma unroll
        for (int r = 0; r < 4; ++r) {
            p0[r] = s0v[r] + (float)ba0[r];
            p1[r] = s1v[r] + (float)ba1[r];
            mt = fmaxf(mt, fmaxf(p0[r], p1[r]));
        }
        mt = fmaxf(mt, __shfl_xor(mt, 16));
        mt = fmaxf(mt, __shfl_xor(mt, 32));
        if (!__all(mt <= m_run + 11.5416f)) {
            float mn = fmaxf(m_run, mt);
            float alpha = exp2f(m_run - mn);
            l_run *= alpha;
#pragma unroll
            for (int d = 0; d < 4; ++d) oacc[d] *= alpha;
            m_run = mn;
        }
        float ps = 0.f;
        bf16x4 pk0, pk1;
#pragma unroll
        for (int r = 0; r < 4; ++r) {
            p0[r] = exp2f(p0[r] - m_run);
            p1[r] = exp2f(p1[r] - m_run);
            ps += p0[r] + p1[r];
            pk0[r] = (bf16)p0[r];
            pk1[r] = (bf16)p1[r];
        }
        ps += __shfl_xor(ps, 16);
        ps += __shfl_xor(ps, 32);
        l_run += ps;

        *(bf16x4*)(pwr + ((lg * 8) ^ kx)) = pk0;
        *(bf16x4*)(pwr + ((32 + lg * 8) ^ kx)) = pk1;
        asm volatile("s_waitcnt lgkmcnt(0)" ::: "memory");
        __builtin_amdgcn_sched_barrier(0x20);
        bf16x8 py = *(bf16x8*)(Pb + w * 1024 + lr * 64 + ((lg * 16) ^ kx));
        __builtin_amdgcn_s_setprio(1);
        oacc[0] = __builtin_amdgcn_mfma_f32_16x16x32_bf16(vx0, py, oacc[0], 0, 0, 0);
        oacc[1] = __builtin_amdgcn_mfma_f32_16x16x32_bf16(vx1, py, oacc[1], 0, 0, 0);
        oacc[2] = __builtin_amdgcn_mfma_f32_16x16x32_bf16(vx2, py, oacc[2], 0, 0, 0);
        oacc[3] = __builtin_amdgcn_mfma_f32_16x16x32_bf16(vx3, py, oacc[3], 0, 0, 0);
        __builtin_amdgcn_s_setprio(0);
        ka0 = kn0; ka1 = kn1; ka2 = kn2; ka3 = kn3;
        ba0 = bn0; ba1 = bn1;
    }

    __syncthreads();
    if (lg == 0) { Msh[ti][s][lr] = m_run; Lsh[ti][s][lr] = l_run; }
    __syncthreads();
    float m0 = Msh[ti][0][lr], m1 = Msh[ti][1][lr], m2 = Msh[ti][2][lr], m3 = Msh[ti][3][lr];
    float mtot = fmaxf(fmaxf(m0, m1), fmaxf(m2, m3));
    float l_tot = Lsh[ti][0][lr] * exp2f(m0 - mtot) + Lsh[ti][1][lr] * exp2f(m1 - mtot)
                + Lsh[ti][2][lr] * exp2f(m2 - mtot) + Lsh[ti][3][lr] * exp2f(m3 - mtot);
    float fac = exp2f(m_run - mtot);
#pragma unroll
    for (int d = 0; d < 4; ++d) oacc[d] *= fac;
    if (s == 0) {
#pragma unroll
        for (int db = 0; db < 4; ++db)
#pragma unroll
            for (int r = 0; r < 4; ++r) Osh[ti][db * 16 + lg * 4 + r][lr] = oacc[db][r];
    }
    __syncthreads();
    if (s == 1) {
#pragma unroll
        for (int db = 0; db < 4; ++db)
#pragma unroll
            for (int r = 0; r < 4; ++r) Osh[ti][db * 16 + lg * 4 + r][lr] += oacc[db][r];
    }
    __syncthreads();
    if (s == 2) {
#pragma unroll
        for (int db = 0; db < 4; ++db)
#pragma unroll
            for (int r = 0; r < 4; ++r) Osh[ti][db * 16 + lg * 4 + r][lr] += oacc[db][r];
    }
    __syncthreads();
    if (s == 3) {
        float inv = 1.f / l_tot;
#pragma unroll
        for (int db = 0; db < 4; ++db) {
            bf16x4 o4;
#pragma unroll
            for (int r = 0; r < 4; ++r)
                o4[r] = (bf16)((Osh[ti][db * 16 + lg * 4 + r][lr] + oacc[db][r]) * inv);
            *(bf16x4*)(ob + (size_t)(irow + lr) * HDIM + hh * DK + db * 16 + lg * 4) = o4;
        }
    }
}

// ---------------- final projection: MFMA, 16-row tiles, 4-way K-split ----------------
__global__ __launch_bounds__(256) void k_fout(const float* __restrict__ h, const bf16* __restrict__ Bt,
                                              const float* __restrict__ bvec, float* __restrict__ C) {
    __shared__ float Osh[16][68];
    int t = threadIdx.x, s = t >> 6, l = t & 63, lr = l & 15, lg = l >> 4;
    int i0 = blockIdx.x * 16;
    const float* ap = h + (size_t)(i0 + lr) * HDIM + s * 128 + lg * 8;
    f32x4 acc[4] = {};
#pragma unroll
    for (int kk = 0; kk < 4; ++kk) {
        float4 f0 = *(const float4*)(ap + kk * 32);
        float4 f1 = *(const float4*)(ap + kk * 32 + 4);
        bf16x8 a;
        a[0] = (bf16)f0.x; a[1] = (bf16)f0.y; a[2] = (bf16)f0.z; a[3] = (bf16)f0.w;
        a[4] = (bf16)f1.x; a[5] = (bf16)f1.y; a[6] = (bf16)f1.z; a[7] = (bf16)f1.w;
#pragma unroll
        for (int sub = 0; sub < 4; ++sub) {
            bf16x8 b = *(const bf16x8*)(Bt + (size_t)(sub * 16 + lr) * HDIM + s * 128 + kk * 32 + lg * 8);
            acc[sub] = __builtin_amdgcn_mfma_f32_16x16x32_bf16(a, b, acc[sub], 0, 0, 0);
        }
    }
    if (s == 0) {
#pragma unroll
        for (int sub = 0; sub < 4; ++sub)
#pragma unroll
            for (int r = 0; r < 4; ++r) Osh[lg * 4 + r][sub * 16 + lr] = acc[sub][r];
    }
    __syncthreads();
    if (s == 1) {
#pragma unroll
        for (int sub = 0; sub < 4; ++sub)
#pragma unroll
            for (int r = 0; r < 4; ++r) Osh[lg * 4 + r][sub * 16 + lr] += acc[sub][r];
    }
    __syncthreads();
    if (s == 2) {
#pragma unroll
        for (int sub = 0; sub < 4; ++sub)
#pragma unroll
            for (int r = 0; r < 4; ++r) Osh[lg * 4 + r][sub * 16 + lr] += acc[sub][r];
    }
    __syncthreads();
    if (s == 3) {
#pragma unroll
        for (int sub = 0; sub < 4; ++sub) {
#pragma unroll
            for (int r = 0; r < 4; ++r) {
                int i = i0 + lg * 4 + r;
                int j = sub * 16 + lr;
                C[(size_t)i * ODIM + j] = Osh[lg * 4 + r][sub * 16 + lr] + acc[sub][r] + bvec[j];
            }
        }
    }
}

extern "C" void kernel_launch(void* const* d_in, const int* in_sizes, int n_in,
                              void* d_out, int out_size, void* d_ws, size_t ws_size,
                              hipStream_t stream) {
    const float* x      = (const float*)d_in[0];
    const int*   ei     = (const int*)d_in[1];
    const float* eattr  = (const float*)d_in[2];
    const int*   epaths = (const int*)d_in[4];
    const float* Wn     = (const float*)d_in[5];
    const float* bn     = (const float*)d_in[6];
    const float* We     = (const float*)d_in[7];
    const float* be     = (const float*)d_in[8];
    const float* zin    = (const float*)d_in[9];
    const float* zout   = (const float*)d_in[10];
    const float* bsp    = (const float*)d_in[11];
    const float* ev     = (const float*)d_in[12];
    const float* ln1s   = (const float*)d_in[13];
    const float* ln1b   = (const float*)d_in[14];
    const float* Wq     = (const float*)d_in[15];
    const float* bq     = (const float*)d_in[16];
    const float* Wk     = (const float*)d_in[17];
    const float* bk     = (const float*)d_in[18];
    const float* Wv     = (const float*)d_in[19];
    const float* bv     = (const float*)d_in[20];
    const float* Wo     = (const float*)d_in[21];
    const float* bo     = (const float*)d_in[22];
    const float* ln2s   = (const float*)d_in[23];
    const float* ln2b   = (const float*)d_in[24];
    const float* W1     = (const float*)d_in[25];
    const float* b1     = (const float*)d_in[26];
    const float* W2     = (const float*)d_in[27];
    const float* b2     = (const float*)d_in[28];
    const float* Wout   = (const float*)d_in[29];
    const float* bout   = (const float*)d_in[30];

    char* base = (char*)d_ws;
    size_t off = 0;
    auto alloc = [&](size_t bytes) { char* p = base + off; off = (off + bytes + 255) & ~(size_t)255; return p; };
    bf16*  bias   = (bf16*)alloc((size_t)N_NODES * N_NODES * 2);
    float* h      = (float*)alloc((size_t)N_NODES * HDIM * 4);
    bf16*  wT     = (bf16*)alloc((size_t)LPATH * NEDGE * 2);
    int*   deg    = (int*)alloc(2 * N_NODES * 4);
    bf16*  WnT    = (bf16*)alloc((size_t)HDIM * FDIM * 2);
    bf16*  WoutT  = (bf16*)alloc((size_t)ODIM * HDIM * 2);
    bf16*  Wt     = (bf16*)alloc((size_t)NLAYER * 6 * HDIM * HDIM * 2);
    bf16*  y_bf   = (bf16*)alloc((size_t)N_NODES * HDIM * 2);
    bf16*  qfb    = (bf16*)alloc((size_t)NHEAD * 128 * 2 * 512 * 2);
    bf16*  kfb    = (bf16*)alloc((size_t)NHEAD * 128 * 2 * 512 * 2);
    bf16*  vfb    = (bf16*)alloc((size_t)NHEAD * 4 * 64 * 512 * 2);
    bf16*  ob_bf  = (bf16*)alloc((size_t)N_NODES * HDIM * 2);
    bf16*  t1_bf  = (bf16*)alloc((size_t)N_NODES * HDIM * 2);
    int* din = deg;
    int* dout = deg + N_NODES;

    hipMemsetAsync(deg, 0, 2 * N_NODES * sizeof(int), stream);

    k_prep<<<1920, 256, 0, stream>>>(eattr, We, be, ev, ei, din, dout, wT,
                                     Wq, Wk, Wv, Wo, W1, W2, Wn, Wout, Wt, WnT, WoutT);
    k_bias3<<<512, 1024, 0, stream>>>(epaths, wT, bsp, bias);
    k_nmm<<<dim3(8, 32), 256, 0, stream>>>(x, WnT, bn, zin, zout, din, dout, h);

    dim3 gqkv(48, 32);
    dim3 gmm(8, 32);

    for (int lay = 0; lay < NLAYER; ++lay) {
        const bf16* Wt_l = Wt + (size_t)lay * 6 * HDIM * HDIM;
        size_t bOff = (size_t)lay * HDIM;
        k_ln<<<512, 256, 0, stream>>>(h, ln1s + bOff, ln1b + bOff, y_bf);
        k_qkv<<<gqkv, 256, 0, stream>>>(y_bf, Wt_l, bq + bOff, bk + bOff, bv + bOff, qfb, kfb, vfb);
        k_attn2<<<256, 1024, 0, stream>>>(qfb, kfb, vfb, bias, ob_bf);
        k_mm<<<gmm, 1024, 0, stream>>>(ob_bf, Wt_l + (size_t)3 * HDIM * HDIM, bo + bOff, h, h, nullptr, FL_RES | FL_OUTF);
        k_mmln<<<gmm, 1024, 0, stream>>>(h, Wt_l + (size_t)4 * HDIM * HDIM, ln2s + bOff, ln2b + bOff, b1 + bOff, t1_bf);
        k_mm<<<gmm, 1024, 0, stream>>>(t1_bf, Wt_l + (size_t)5 * HDIM * HDIM, b2 + bOff, h, h, nullptr, FL_RES | FL_OUTF);
    }
    k_fout<<<128, 256, 0, stream>>>(h, WoutT, bout, (float*)d_out);
}

// Round 16
// 451.594 us; speedup vs baseline: 1.4150x; 1.0077x over previous
//
#include <hip/hip_runtime.h>
#include <hip/hip_bf16.h>
#include <math.h>

#define N_NODES 2048
#define NEDGE   65536
#define FDIM    128
#define HDIM    512
#define EFD     16
#define EDD     64
#define LPATH   5
#define NLAYER  4
#define NHEAD   8
#define DK      64
#define ODIM    64
#define MAXDEG  64
#define PTOT    4194304
#define LOG2E   1.4426950408889634f

typedef __bf16 bf16;
typedef bf16 bf16x8 __attribute__((ext_vector_type(8)));
typedef bf16 bf16x4 __attribute__((ext_vector_type(4)));
typedef float f32x4 __attribute__((ext_vector_type(4)));
typedef unsigned short u16;

// ---------------- fused prep: blocks [0,256) = edge weights + degrees; [256,1920) = weight transposes ----------------
__global__ __launch_bounds__(256) void k_prep(const float* __restrict__ ea, const float* __restrict__ We,
                                              const float* __restrict__ be, const float* __restrict__ ev,
                                              const int* __restrict__ ei, int* __restrict__ din,
                                              int* __restrict__ dout, bf16* __restrict__ wT,
                                              const float* __restrict__ Wq, const float* __restrict__ Wk,
                                              const float* __restrict__ Wv, const float* __restrict__ Wo,
                                              const float* __restrict__ W1, const float* __restrict__ W2,
                                              const float* __restrict__ Wn, const float* __restrict__ Wout,
                                              bf16* __restrict__ Wt, bf16* __restrict__ WnT,
                                              bf16* __restrict__ WoutT) {
    __shared__ float sM[80];
    __shared__ float sc[8];
    __shared__ float Ls[64][68];
    int t = threadIdx.x;
    int bx = blockIdx.x;
    if (bx < 256) {
        if (t < 80) {
            int i = t / 5, j = t % 5;
            float acc = 0.f;
            for (int k = 0; k < EDD; ++k) acc += We[i * EDD + k] * ev[j * EDD + k];
            sM[t] = acc;
        } else if (t >= 128 && t < 128 + LPATH) {
            int j = t - 128;
            float acc = 0.f;
            for (int k = 0; k < EDD; ++k) acc += be[k] * ev[j * EDD + k];
            sc[j] = acc;
        }
        int e = bx * 256 + t;
        atomicAdd(&dout[ei[e]], 1);
        atomicAdd(&din[ei[NEDGE + e]], 1);
        __syncthreads();
        const float4* p = (const float4*)(ea + (size_t)e * EFD);
        float4 a0 = p[0], a1 = p[1], a2 = p[2], a3 = p[3];
        float a[16] = {a0.x, a0.y, a0.z, a0.w, a1.x, a1.y, a1.z, a1.w,
                       a2.x, a2.y, a2.z, a2.w, a3.x, a3.y, a3.z, a3.w};
        float out[LPATH];
#pragma unroll
        for (int j = 0; j < LPATH; ++j) out[j] = sc[j];
#pragma unroll
        for (int i = 0; i < 16; ++i)
#pragma unroll
            for (int j = 0; j < LPATH; ++j) out[j] += a[i] * sM[i * LPATH + j];
#pragma unroll
        for (int j = 0; j < LPATH; ++j) wT[(size_t)j * NEDGE + e] = (bf16)out[j];
        return;
    }
    int m = (bx - 256) >> 6;
    int q = (bx - 256) & 63;
    int rr = t >> 4, cc = t & 15;
    int nl = t >> 2, kc = t & 3;
    if (m < 24) {
        int lay = m / 6, type = m % 6;
        const float* src = type == 0 ? Wq : type == 1 ? Wk : type == 2 ? Wv : type == 3 ? Wo : type == 4 ? W1 : W2;
        src += (size_t)lay * (HDIM * HDIM);
        int tk = q >> 3, tn = q & 7;
#pragma unroll
        for (int u = 0; u < 4; ++u) {
            float4 v = *(const float4*)(src + (size_t)(tk * 64 + rr + 16 * u) * HDIM + tn * 64 + cc * 4);
            *(float4*)&Ls[rr + 16 * u][cc * 4] = v;
        }
        __syncthreads();
        bf16 tmp[16];
#pragma unroll
        for (int u = 0; u < 16; ++u) tmp[u] = (bf16)Ls[kc * 16 + u][nl];
        bf16* dst = Wt + (size_t)m * (HDIM * HDIM) + (size_t)(tn * 64 + nl) * HDIM + tk * 64 + kc * 16;
        *(bf16x8*)(dst) = *(bf16x8*)&tmp[0];
        *(bf16x8*)(dst + 8) = *(bf16x8*)&tmp[8];
    } else if (m == 24) {
        if (q >= 16) return;
        int tk = q >> 3, tn = q & 7;
#pragma unroll
        for (int u = 0; u < 4; ++u) {
            float4 v = *(const float4*)(Wn + (size_t)(tk * 64 + rr + 16 * u) * HDIM + tn * 64 + cc * 4);
            *(float4*)&Ls[rr + 16 * u][cc * 4] = v;
        }
        __syncthreads();
        bf16 tmp[16];
#pragma unroll
        for (int u = 0; u < 16; ++u) tmp[u] = (bf16)Ls[kc * 16 + u][nl];
        bf16* dst = WnT + (size_t)(tn * 64 + nl) * FDIM + tk * 64 + kc * 16;
        *(bf16x8*)dst = *(bf16x8*)&tmp[0];
        *(bf16x8*)(dst + 8) = *(bf16x8*)&tmp[8];
    } else {
        if (q >= 8) return;
        int tk = q;
#pragma unroll
        for (int u = 0; u < 4; ++u) {
            float4 v = *(const float4*)(Wout + (size_t)(tk * 64 + rr + 16 * u) * ODIM + cc * 4);
            *(float4*)&Ls[rr + 16 * u][cc * 4] = v;
        }
        __syncthreads();
        bf16 tmp[16];
#pragma unroll
        for (int u = 0; u < 16; ++u) tmp[u] = (bf16)Ls[kc * 16 + u][nl];
        bf16* dst = WoutT + (size_t)nl * HDIM + tk * 64 + kc * 16;
        *(bf16x8*)dst = *(bf16x8*)&tmp[0];
        *(bf16x8*)(dst + 8) = *(bf16x8*)&tmp[8];
    }
}

// ---------------- bias: r8 structure (single 8192-pair chunk, spill-free). Output bias * LOG2E ----------------
__global__ __launch_bounds__(1024) void k_bias3(const int* __restrict__ ep, const bf16* __restrict__ wT,
                                                const float* __restrict__ bsp, bf16* __restrict__ bias) {
    __shared__ char lds[163840];
    int t = threadIdx.x;
    size_t basep = (size_t)blockIdx.x * 8192;
    int* ish = (int*)lds;
    const int4* src = (const int4*)(ep + basep * 5);
#pragma unroll
    for (int u = 0; u < 10; ++u) ((int4*)ish)[t + 1024 * u] = src[t + 1024 * u];
    __syncthreads();
    unsigned pa[8], pb[8], pc[8];
#pragma unroll
    for (int r = 0; r < 8; ++r) {
        int p5 = (r * 1024 + t) * 5;
        int e0 = ish[p5], e1 = ish[p5 + 1], e2 = ish[p5 + 2], e3 = ish[p5 + 3], e4 = ish[p5 + 4];
        unsigned mk = (unsigned)(e0 >= 0) | ((unsigned)(e1 >= 0) << 1) | ((unsigned)(e2 >= 0) << 2)
                    | ((unsigned)(e3 >= 0) << 3) | ((unsigned)(e4 >= 0) << 4);
        pa[r] = ((unsigned)e0 & 0xFFFFu) | ((unsigned)e1 << 16);
        pb[r] = ((unsigned)e2 & 0xFFFFu) | ((unsigned)e3 << 16);
        pc[r] = ((unsigned)e4 & 0xFFFFu) | (mk << 16);
    }
    bf16* wsl = (bf16*)lds;
    float csum[8] = {};
#pragma unroll
    for (int l = 0; l < LPATH; ++l) {
        __syncthreads();
#pragma unroll
        for (int u = 0; u < 4; ++u) {
            int o = u * 16384 + t * 16;
            *(bf16x8*)&wsl[o]     = *(const bf16x8*)&wT[(size_t)l * NEDGE + o];
            *(bf16x8*)&wsl[o + 8] = *(const bf16x8*)&wT[(size_t)l * NEDGE + o + 8];
        }
        __syncthreads();
#pragma unroll
        for (int r = 0; r < 8; ++r) {
            unsigned ix = (l == 0) ? (pa[r] & 0xFFFFu) : (l == 1) ? (pa[r] >> 16)
                        : (l == 2) ? (pb[r] & 0xFFFFu) : (l == 3) ? (pb[r] >> 16) : (pc[r] & 0xFFFFu);
            float v = (float)wsl[ix];
            csum[r] += ((pc[r] >> (16 + l)) & 1u) ? v : 0.f;
        }
    }
#pragma unroll
    for (int r = 0; r < 8; ++r) {
        int cnt = __popc((int)((pc[r] >> 16) & 0x1Fu));
        float b = cnt ? (bsp[cnt - 1] + csum[r] / (float)cnt) * LOG2E : 0.f;
        bias[basep + r * 1024 + t] = (bf16)b;
    }
}

// ---------------- layernorm (LN1): wave-per-row, shuffle-only ----------------
__global__ __launch_bounds__(256) void k_ln(const float* __restrict__ h, const float* __restrict__ sc,
                                            const float* __restrict__ bi, bf16* __restrict__ y) {
    int t = threadIdx.x, w = t >> 6, l = t & 63;
    int row = blockIdx.x * 4 + w;
    const float* hp = h + (size_t)row * HDIM + l * 8;
    float4 a = *(const float4*)hp;
    float4 b = *(const float4*)(hp + 4);
    float s = a.x + a.y + a.z + a.w + b.x + b.y + b.z + b.w;
    float q = a.x * a.x + a.y * a.y + a.z * a.z + a.w * a.w
            + b.x * b.x + b.y * b.y + b.z * b.z + b.w * b.w;
#pragma unroll
    for (int m = 1; m < 64; m <<= 1) { s += __shfl_xor(s, m); q += __shfl_xor(q, m); }
    float mean = s * (1.f / HDIM);
    float var = q * (1.f / HDIM) - mean * mean;
    float r = rsqrtf(var + 1e-5f);
    float4 s0 = *(const float4*)(sc + l * 8), s1 = *(const float4*)(sc + l * 8 + 4);
    float4 b0 = *(const float4*)(bi + l * 8), b1 = *(const float4*)(bi + l * 8 + 4);
    float va[8] = {a.x, a.y, a.z, a.w, b.x, b.y, b.z, b.w};
    float ss[8] = {s0.x, s0.y, s0.z, s0.w, s1.x, s1.y, s1.z, s1.w};
    float bb[8] = {b0.x, b0.y, b0.z, b0.w, b1.x, b1.y, b1.z, b1.w};
    bf16x8 o;
#pragma unroll
    for (int c = 0; c < 8; ++c) o[c] = (bf16)((va[c] - mean) * r * ss[c] + bb[c]);
    *(bf16x8*)(y + (size_t)row * HDIM + l * 8) = o;
}

// node projection as MFMA GEMM (K=128, f32 x inline-cast) + degree-embedding epilogue
__global__ __launch_bounds__(256) void k_nmm(const float* __restrict__ x, const bf16* __restrict__ Bt,
                                             const float* __restrict__ bn, const float* __restrict__ zin,
                                             const float* __restrict__ zout, const int* __restrict__ din,
                                             const int* __restrict__ dout, float* __restrict__ h) {
    __shared__ bf16 Bs[8192];
    int t = threadIdx.x, w = t >> 6, l = t & 63, lr = l & 15, lg = l >> 4;
    int j0 = blockIdx.x * 64, i0 = blockIdx.y * 64;
    const bf16* Bp = Bt + (size_t)j0 * FDIM;
#pragma unroll
    for (int rnd = 0; rnd < 4; ++rnd) {
        int tt = rnd * 256 + t;
        int ks = tt >> 8, qq = (tt >> 6) & 3, mm = (tt >> 2) & 15, gg = tt & 3;
        *(bf16x8*)(Bs + tt * 8) = *(const bf16x8*)(Bp + (size_t)(qq * 16 + mm) * FDIM + ks * 32 + gg * 8);
    }
    __syncthreads();
    const float* ap = x + (size_t)(i0 + w * 16 + lr) * FDIM + 8 * lg;
    f32x4 acc[4] = {};
#pragma unroll
    for (int ks = 0; ks < 4; ++ks) {
        float4 f0 = *(const float4*)(ap + ks * 32);
        float4 f1 = *(const float4*)(ap + ks * 32 + 4);
        bf16x8 a;
        a[0] = (bf16)f0.x; a[1] = (bf16)f0.y; a[2] = (bf16)f0.z; a[3] = (bf16)f0.w;
        a[4] = (bf16)f1.x; a[5] = (bf16)f1.y; a[6] = (bf16)f1.z; a[7] = (bf16)f1.w;
        const bf16* bb = Bs + ks * 2048 + lr * 32 + lg * 8;
#pragma unroll
        for (int sub = 0; sub < 4; ++sub)
            acc[sub] = __builtin_amdgcn_mfma_f32_16x16x32_bf16(a, *(const bf16x8*)(bb + sub * 512), acc[sub], 0, 0, 0);
    }
#pragma unroll
    for (int r = 0; r < 4; ++r) {
        int i = i0 + w * 16 + lg * 4 + r;
        int di = min(din[i], MAXDEG - 1), dz = min(dout[i], MAXDEG - 1);
#pragma unroll
        for (int sub = 0; sub < 4; ++sub) {
            int j = j0 + sub * 16 + lr;
            h[(size_t)i * HDIM + j] = acc[sub][r] + bn[j] + zin[(size_t)di * HDIM + j] + zout[(size_t)dz * HDIM + j];
        }
    }
}

// ---------------- fused QKV GEMM -> frag-contiguous q/k/v layouts ----------------
// q pre-scaled by 0.125*LOG2E (attn softmax in exp2 domain)
__global__ __launch_bounds__(256) void k_qkv(const bf16* __restrict__ A, const bf16* __restrict__ Wt_l,
                                             const float* __restrict__ bq, const float* __restrict__ bk,
                                             const float* __restrict__ bv, bf16* __restrict__ qf,
                                             bf16* __restrict__ kf, bf16* __restrict__ vf) {
    __shared__ bf16 Bs[16384];
    int t = threadIdx.x, w = t >> 6, l = t & 63, lr = l & 15, lg = l >> 4;
    int j0 = blockIdx.x * 32, i0 = blockIdx.y * 64;
    int type = j0 >> 9, n0 = j0 & 511;
    const bf16* Bp = Wt_l + (size_t)type * (HDIM * HDIM) + (size_t)n0 * HDIM;
#pragma unroll
    for (int rnd = 0; rnd < 8; ++rnd) {
        int tt = rnd * 256 + t;
        int ks = tt >> 7, qq = (tt >> 6) & 1, mm = (tt >> 2) & 15, gg = tt & 3;
        bf16x8 v = *(const bf16x8*)(Bp + (size_t)(qq * 16 + mm) * HDIM + ks * 32 + gg * 8);
        *(bf16x8*)(Bs + tt * 8) = v;
    }
    __syncthreads();
    const bf16* ap = A + (size_t)(i0 + w * 16 + lr) * HDIM + 8 * lg;
    const float* bvec = (type == 0 ? bq : type == 1 ? bk : bv);
    f32x4 acc[2] = {};
#pragma unroll 4
    for (int ks = 0; ks < 16; ++ks) {
        bf16x8 a  = *(const bf16x8*)(ap + ks * 32);
        const bf16* bb = Bs + ks * 1024 + lr * 32 + lg * 8;
        bf16x8 b0 = *(const bf16x8*)(bb);
        bf16x8 b1 = *(const bf16x8*)(bb + 512);
        acc[0] = __builtin_amdgcn_mfma_f32_16x16x32_bf16(a, b0, acc[0], 0, 0, 0);
        acc[1] = __builtin_amdgcn_mfma_f32_16x16x32_bf16(a, b1, acc[1], 0, 0, 0);
    }
    int h = n0 >> 6;
    if (type < 2) {
        bf16* dst = (type == 0 ? qf : kf);
        int hf = (n0 & 32) >> 5;
        float sc = (type == 0 ? 0.125f * LOG2E : 1.0f);
#pragma unroll
        for (int sub = 0; sub < 2; ++sub) {
#pragma unroll
            for (int r = 0; r < 4; ++r) {
                int i = i0 + w * 16 + lg * 4 + r;
                float v = (acc[sub][r] + bvec[n0 + sub * 16 + lr]) * sc;
                int lgp = sub * 2 + (lr >> 3);
                size_t off = (((size_t)(h * 128 + (i >> 4)) * 2 + hf) << 9) + lgp * 128 + (lg * 4 + r) * 8 + (lr & 7);
                dst[off] = (bf16)v;
            }
        }
    } else {
#pragma unroll
        for (int sub = 0; sub < 2; ++sub) {
#pragma unroll
            for (int r = 0; r < 4; ++r) {
                int node = i0 + w * 16 + lg * 4 + r;
                int dd = (n0 & 63) + sub * 16 + lr;
                float v = acc[sub][r] + bvec[n0 + sub * 16 + lr];
                size_t off = (((size_t)(h * 4 + (dd >> 4)) * 64 + (node >> 5)) << 9)
                           + ((node >> 3) & 3) * 128 + (dd & 15) * 8 + (node & 7);
                vf[off] = (bf16)v;
            }
        }
    }
}

// ---------------- generic bf16 MFMA GEMM, BN=64, 16 waves, 4-way K-split ----------------
#define FL_RES   1
#define FL_GELU  2
#define FL_OUTF  4

__device__ inline float gelu_f(float x) {
    float x3 = x * x * x;
    float u = 0.7978845608028654f * (x + 0.044715f * x3);
    return 0.5f * x * (1.f + tanhf(u));
}

__global__ __launch_bounds__(1024) void k_mm(const bf16* __restrict__ A, const bf16* __restrict__ Bt,
                                             const float* __restrict__ bvec, const float* __restrict__ res,
                                             float* __restrict__ outF, bf16* __restrict__ outB, int flags) {
    __shared__ bf16 Bs[32768];
    __shared__ float Osh[4][16][68];
    int t = threadIdx.x, w = t >> 6, l = t & 63, lr = l & 15, lg = l >> 4;
    int ti = w & 3, s = w >> 2;
    int j0 = blockIdx.x * 64, i0 = blockIdx.y * 64;
    const bf16* Bp = Bt + (size_t)j0 * HDIM;
#pragma unroll
    for (int rnd = 0; rnd < 4; ++rnd) {
        int tt = rnd * 1024 + t;
        int ks = tt >> 8, qq = (tt >> 6) & 3, mm = (tt >> 2) & 15, gg = tt & 3;
        bf16x8 v = *(const bf16x8*)(Bp + (size_t)(qq * 16 + mm) * HDIM + ks * 32 + gg * 8);
        *(bf16x8*)(Bs + tt * 8) = v;
    }
    __syncthreads();
    const bf16* ap = A + (size_t)(i0 + ti * 16 + lr) * HDIM + 8 * lg;
    f32x4 acc[4] = {};
#pragma unroll
    for (int kk = 0; kk < 4; ++kk) {
        int ks = s * 4 + kk;
        bf16x8 a = *(const bf16x8*)(ap + ks * 32);
        const bf16* bb = Bs + ks * 2048 + lr * 32 + lg * 8;
#pragma unroll
        for (int sub = 0; sub < 4; ++sub) {
            bf16x8 b = *(const bf16x8*)(bb + sub * 512);
            acc[sub] = __builtin_amdgcn_mfma_f32_16x16x32_bf16(a, b, acc[sub], 0, 0, 0);
        }
    }
    if (s == 0) {
#pragma unroll
        for (int sub = 0; sub < 4; ++sub)
#pragma unroll
            for (int r = 0; r < 4; ++r) Osh[ti][lg * 4 + r][sub * 16 + lr] = acc[sub][r];
    }
    __syncthreads();
    if (s == 1) {
#pragma unroll
        for (int sub = 0; sub < 4; ++sub)
#pragma unroll
            for (int r = 0; r < 4; ++r) Osh[ti][lg * 4 + r][sub * 16 + lr] += acc[sub][r];
    }
    __syncthreads();
    if (s == 2) {
#pragma unroll
        for (int sub = 0; sub < 4; ++sub)
#pragma unroll
            for (int r = 0; r < 4; ++r) Osh[ti][lg * 4 + r][sub * 16 + lr] += acc[sub][r];
    }
    __syncthreads();
    if (s == 3) {
#pragma unroll
        for (int sub = 0; sub < 4; ++sub) {
#pragma unroll
            for (int r = 0; r < 4; ++r) {
                int i = i0 + ti * 16 + lg * 4 + r;
                int j = j0 + sub * 16 + lr;
                float v = Osh[ti][lg * 4 + r][sub * 16 + lr] + acc[sub][r] + bvec[j];
                if (flags & FL_RES) v += res[(size_t)i * HDIM + j];
                if (flags & FL_GELU) v = gelu_f(v);
                if (flags & FL_OUTF) outF[(size_t)i * HDIM + j] = v;
                else outB[(size_t)i * HDIM + j] = (bf16)v;
            }
        }
    }
}

// ---------------- LN2 + FFN1 fused ----------------
__global__ __launch_bounds__(1024) void k_mmln(const float* __restrict__ h, const bf16* __restrict__ Bt,
                                               const float* __restrict__ lnS, const float* __restrict__ lnB,
                                               const float* __restrict__ bvec, bf16* __restrict__ outB) {
    __shared__ bf16 As[32768];
    __shared__ bf16 Bs[32768];
    __shared__ float Osh[4][16][68];
    __shared__ float sbuf[HDIM], bbuf[HDIM];
    int t = threadIdx.x, w = t >> 6, l = t & 63, lr = l & 15, lg = l >> 4;
    int ti = w & 3, s = w >> 2;
    int j0 = blockIdx.x * 64, i0 = blockIdx.y * 64;
    if (t < HDIM) sbuf[t] = lnS[t];
    else bbuf[t - HDIM] = lnB[t - HDIM];
    const bf16* Bp = Bt + (size_t)j0 * HDIM;
#pragma unroll
    for (int rnd = 0; rnd < 4; ++rnd) {
        int tt = rnd * 1024 + t;
        int ks = tt >> 8, qq = (tt >> 6) & 3, mm = (tt >> 2) & 15, gg = tt & 3;
        *(bf16x8*)(Bs + tt * 8) = *(const bf16x8*)(Bp + (size_t)(qq * 16 + mm) * HDIM + ks * 32 + gg * 8);
    }
    int row = t >> 4, ksc = t & 15;
    const float* hp = h + (size_t)(i0 + row) * HDIM + ksc * 32;
    float4 hv[8];
    float S = 0.f, Q = 0.f;
#pragma unroll
    for (int u = 0; u < 8; ++u) {
        hv[u] = *(const float4*)(hp + u * 4);
        S += hv[u].x + hv[u].y + hv[u].z + hv[u].w;
        Q += hv[u].x * hv[u].x + hv[u].y * hv[u].y + hv[u].z * hv[u].z + hv[u].w * hv[u].w;
    }
#pragma unroll
    for (int m = 1; m < 16; m <<= 1) { S += __shfl_xor(S, m); Q += __shfl_xor(Q, m); }
    float mean = S * (1.f / HDIM);
    float var = Q * (1.f / HDIM) - mean * mean;
    float rr = rsqrtf(var + 1e-5f);
    float ca = rr, cc = -mean * rr;
    __syncthreads();
    {
        bf16 tmp[32];
#pragma unroll
        for (int u = 0; u < 8; ++u) {
            float vv[4] = {hv[u].x, hv[u].y, hv[u].z, hv[u].w};
#pragma unroll
            for (int c = 0; c < 4; ++c) {
                int col = ksc * 32 + u * 4 + c;
                tmp[u * 4 + c] = (bf16)(fmaf(fmaf(vv[c], ca, cc), sbuf[col], bbuf[col]));
            }
        }
        bf16* dst = As + (row >> 4) * 8192 + ksc * 512 + (row & 15) * 32;
#pragma unroll
        for (int u = 0; u < 4; ++u) *(bf16x8*)(dst + u * 8) = *(bf16x8*)&tmp[u * 8];
    }
    __syncthreads();
    const bf16* apl = As + ti * 8192 + lr * 32 + lg * 8;
    f32x4 acc[4] = {};
#pragma unroll
    for (int kk = 0; kk < 4; ++kk) {
        int ks = s * 4 + kk;
        bf16x8 a = *(const bf16x8*)(apl + ks * 512);
        const bf16* bb = Bs + ks * 2048 + lr * 32 + lg * 8;
#pragma unroll
        for (int sub = 0; sub < 4; ++sub)
            acc[sub] = __builtin_amdgcn_mfma_f32_16x16x32_bf16(a, *(const bf16x8*)(bb + sub * 512), acc[sub], 0, 0, 0);
    }
    if (s == 0) {
#pragma unroll
        for (int sub = 0; sub < 4; ++sub)
#pragma unroll
            for (int r = 0; r < 4; ++r) Osh[ti][lg * 4 + r][sub * 16 + lr] = acc[sub][r];
    }
    __syncthreads();
    if (s == 1) {
#pragma unroll
        for (int sub = 0; sub < 4; ++sub)
#pragma unroll
            for (int r = 0; r < 4; ++r) Osh[ti][lg * 4 + r][sub * 16 + lr] += acc[sub][r];
    }
    __syncthreads();
    if (s == 2) {
#pragma unroll
        for (int sub = 0; sub < 4; ++sub)
#pragma unroll
            for (int r = 0; r < 4; ++r) Osh[ti][lg * 4 + r][sub * 16 + lr] += acc[sub][r];
    }
    __syncthreads();
    if (s == 3) {
#pragma unroll
        for (int sub = 0; sub < 4; ++sub) {
#pragma unroll
            for (int r = 0; r < 4; ++r) {
                int i = i0 + ti * 16 + lg * 4 + r;
                int j = j0 + sub * 16 + lr;
                float v = gelu_f(Osh[ti][lg * 4 + r][sub * 16 + lr] + acc[sub][r] + bvec[j]);
                outB[(size_t)i * HDIM + j] = (bf16)v;
            }
        }
    }
}

// ---------------- attention: swapped-QK flash, exp2-domain softmax, deferred cross-lane reductions ----------------
__global__ __launch_bounds__(1024) void k_attn2(const bf16* __restrict__ qf, const bf16* __restrict__ kf,
                                                const bf16* __restrict__ vf, const bf16* __restrict__ biasb,
                                                bf16* __restrict__ ob) {
    __shared__ char Pb[16 * 1024];
    __shared__ float Osh[4][64][17];
    __shared__ float Msh[4][4][16], Lsh[4][4][16];
    int t = threadIdx.x, w = t >> 6, l = t & 63, lr = l & 15, lg = l >> 4;
    int ti = w & 3, s = w >> 2;
    int bid = blockIdx.x;
    int wid = (bid & 7) * 32 + (bid >> 3);
    int i0 = (wid >> 3) * 64, hh = wid & 7;
    int irow = i0 + ti * 16;

    const bf16* qb = qf + (((size_t)(hh * 128 + (irow >> 4)) * 2) << 9) + l * 8;
    bf16x8 qy0 = *(const bf16x8*)(qb);
    bf16x8 qy1 = *(const bf16x8*)(qb + 512);

    char* pwr = Pb + w * 1024 + lr * 64;
    unsigned kx = (unsigned)(lr & 6) << 3;

    float m_run = -3e38f, l_run = 0.f;   // l_run is a per-thread partial (reduced after the loop)
    f32x4 oacc[4] = {};

    int jb0 = s * 512;
    const bf16* kbp = kf + (((size_t)(hh * 128 + (jb0 >> 4)) * 2) << 9) + l * 8;
    bf16x8 ka0 = *(const bf16x8*)(kbp);
    bf16x8 ka1 = *(const bf16x8*)(kbp + 512);
    bf16x8 ka2 = *(const bf16x8*)(kbp + 1024);
    bf16x8 ka3 = *(const bf16x8*)(kbp + 1536);
    const bf16* bpp = biasb + (size_t)(irow + lr) * N_NODES + jb0 + lg * 4;
    bf16x4 ba0 = *(const bf16x4*)(bpp);
    bf16x4 ba1 = *(const bf16x4*)(bpp + 16);

    for (int it = 0; it < 16; ++it) {
        int jb = s * 512 + it * 32;
        const bf16* vb = vf + (((size_t)(hh * 4) * 64 + (jb >> 5)) << 9) + l * 8;
        bf16x8 vx0 = *(const bf16x8*)(vb);
        bf16x8 vx1 = *(const bf16x8*)(vb + 32768);
        bf16x8 vx2 = *(const bf16x8*)(vb + 65536);
        bf16x8 vx3 = *(const bf16x8*)(vb + 98304);
        bf16x8 kn0, kn1, kn2, kn3;
        bf16x4 bn0, bn1;
        if (it < 15) {
            int jn = jb + 32;
            const bf16* kbn = kf + (((size_t)(hh * 128 + (jn >> 4)) * 2) << 9) + l * 8;
            kn0 = *(const bf16x8*)(kbn);
            kn1 = *(const bf16x8*)(kbn + 512);
            kn2 = *(const bf16x8*)(kbn + 1024);
            kn3 = *(const bf16x8*)(kbn + 1536);
            const bf16* bpn = biasb + (size_t)(irow + lr) * N_NODES + jn + lg * 4;
            bn0 = *(const bf16x4*)(bpn);
            bn1 = *(const bf16x4*)(bpn + 16);
        }

        f32x4 s0v = {}, s1v = {};
        __builtin_amdgcn_s_setprio(1);
        s0v = __builtin_amdgcn_mfma_f32_16x16x32_bf16(ka0, qy0, s0v, 0, 0, 0);
        s0v = __builtin_amdgcn_mfma_f32_16x16x32_bf16(ka1, qy1, s0v, 0, 0, 0);
        s1v = __builtin_amdgcn_mfma_f32_16x16x32_bf16(ka2, qy0, s1v, 0, 0, 0);
        s1v = __builtin_amdgcn_mfma_f32_16x16x32_bf16(ka3, qy1, s1v, 0, 0, 0);
        __builtin_amdgcn_s_setprio(0);

        float p0[4], p1[4];
        float mt = -3e38f;   // per-thread local max (8 values); wave-wide __all covers all lanes
#pragma unroll
        for (int r = 0; r < 4; ++r) {
            p0[r] = s0v[r] + (float)ba0[r];
            p1[r] = s1v[r] + (float)ba1[r];
            mt = fmaxf(mt, fmaxf(p0[r], p1[r]));
        }
        if (!__all(mt <= m_run + 11.5416f)) {   // 8 * log2(e)
            // rare path: establish row-uniform max across the 4 lg-groups
            mt = fmaxf(mt, __shfl_xor(mt, 16));
            mt = fmaxf(mt, __shfl_xor(mt, 32));
            float mn = fmaxf(m_run, mt);
            float alpha = exp2f(m_run - mn);   // row-uniform
            l_run *= alpha;
#pragma unroll
            for (int d = 0; d < 4; ++d) oacc[d] *= alpha;
            m_run = mn;
        }
        float ps = 0.f;
        bf16x4 pk0, pk1;
#pragma unroll
        for (int r = 0; r < 4; ++r) {
            p0[r] = exp2f(p0[r] - m_run);
            p1[r] = exp2f(p1[r] - m_run);
            ps += p0[r] + p1[r];
            pk0[r] = (bf16)p0[r];
            pk1[r] = (bf16)p1[r];
        }
        l_run += ps;   // per-thread partial; no per-iter shuffles

        *(bf16x4*)(pwr + ((lg * 8) ^ kx)) = pk0;
        *(bf16x4*)(pwr + ((32 + lg * 8) ^ kx)) = pk1;
        asm volatile("s_waitcnt lgkmcnt(0)" ::: "memory");
        __builtin_amdgcn_sched_barrier(0x20);
        bf16x8 py = *(bf16x8*)(Pb + w * 1024 + lr * 64 + ((lg * 16) ^ kx));
        __builtin_amdgcn_s_setprio(1);
        oacc[0] = __builtin_amdgcn_mfma_f32_16x16x32_bf16(vx0, py, oacc[0], 0, 0, 0);
        oacc[1] = __builtin_amdgcn_mfma_f32_16x16x32_bf16(vx1, py, oacc[1], 0, 0, 0);
        oacc[2] = __builtin_amdgcn_mfma_f32_16x16x32_bf16(vx2, py, oacc[2], 0, 0, 0);
        oacc[3] = __builtin_amdgcn_mfma_f32_16x16x32_bf16(vx3, py, oacc[3], 0, 0, 0);
        __builtin_amdgcn_s_setprio(0);
        ka0 = kn0; ka1 = kn1; ka2 = kn2; ka3 = kn3;
        ba0 = bn0; ba1 = bn1;
    }

    // final cross-lg reduce of the row sum (m_run is already row-uniform)
    l_run += __shfl_xor(l_run, 16);
    l_run += __shfl_xor(l_run, 32);

    __syncthreads();
    if (lg == 0) { Msh[ti][s][lr] = m_run; Lsh[ti][s][lr] = l_run; }
    __syncthreads();
    float m0 = Msh[ti][0][lr], m1 = Msh[ti][1][lr], m2 = Msh[ti][2][lr], m3 = Msh[ti][3][lr];
    float mtot = fmaxf(fmaxf(m0, m1), fmaxf(m2, m3));
    float l_tot = Lsh[ti][0][lr] * exp2f(m0 - mtot) + Lsh[ti][1][lr] * exp2f(m1 - mtot)
                + Lsh[ti][2][lr] * exp2f(m2 - mtot) + Lsh[ti][3][lr] * exp2f(m3 - mtot);
    float fac = exp2f(m_run - mtot);
#pragma unroll
    for (int d = 0; d < 4; ++d) oacc[d] *= fac;
    if (s == 0) {
#pragma unroll
        for (int db = 0; db < 4; ++db)
#pragma unroll
            for (int r = 0; r < 4; ++r) Osh[ti][db * 16 + lg * 4 + r][lr] = oacc[db][r];
    }
    __syncthreads();
    if (s == 1) {
#pragma unroll
        for (int db = 0; db < 4; ++db)
#pragma unroll
            for (int r = 0; r < 4; ++r) Osh[ti][db * 16 + lg * 4 + r][lr] += oacc[db][r];
    }
    __syncthreads();
    if (s == 2) {
#pragma unroll
        for (int db = 0; db < 4; ++db)
#pragma unroll
            for (int r = 0; r < 4; ++r) Osh[ti][db * 16 + lg * 4 + r][lr] += oacc[db][r];
    }
    __syncthreads();
    if (s == 3) {
        float inv = 1.f / l_tot;
#pragma unroll
        for (int db = 0; db < 4; ++db) {
            bf16x4 o4;
#pragma unroll
            for (int r = 0; r < 4; ++r)
                o4[r] = (bf16)((Osh[ti][db * 16 + lg * 4 + r][lr] + oacc[db][r]) * inv);
            *(bf16x4*)(ob + (size_t)(irow + lr) * HDIM + hh * DK + db * 16 + lg * 4) = o4;
        }
    }
}

// ---------------- final projection: MFMA, 16-row tiles, 4-way K-split ----------------
__global__ __launch_bounds__(256) void k_fout(const float* __restrict__ h, const bf16* __restrict__ Bt,
                                              const float* __restrict__ bvec, float* __restrict__ C) {
    __shared__ float Osh[16][68];
    int t = threadIdx.x, s = t >> 6, l = t & 63, lr = l & 15, lg = l >> 4;
    int i0 = blockIdx.x * 16;
    const float* ap = h + (size_t)(i0 + lr) * HDIM + s * 128 + lg * 8;
    f32x4 acc[4] = {};
#pragma unroll
    for (int kk = 0; kk < 4; ++kk) {
        float4 f0 = *(const float4*)(ap + kk * 32);
        float4 f1 = *(const float4*)(ap + kk * 32 + 4);
        bf16x8 a;
        a[0] = (bf16)f0.x; a[1] = (bf16)f0.y; a[2] = (bf16)f0.z; a[3] = (bf16)f0.w;
        a[4] = (bf16)f1.x; a[5] = (bf16)f1.y; a[6] = (bf16)f1.z; a[7] = (bf16)f1.w;
#pragma unroll
        for (int sub = 0; sub < 4; ++sub) {
            bf16x8 b = *(const bf16x8*)(Bt + (size_t)(sub * 16 + lr) * HDIM + s * 128 + kk * 32 + lg * 8);
            acc[sub] = __builtin_amdgcn_mfma_f32_16x16x32_bf16(a, b, acc[sub], 0, 0, 0);
        }
    }
    if (s == 0) {
#pragma unroll
        for (int sub = 0; sub < 4; ++sub)
#pragma unroll
            for (int r = 0; r < 4; ++r) Osh[lg * 4 + r][sub * 16 + lr] = acc[sub][r];
    }
    __syncthreads();
    if (s == 1) {
#pragma unroll
        for (int sub = 0; sub < 4; ++sub)
#pragma unroll
            for (int r = 0; r < 4; ++r) Osh[lg * 4 + r][sub * 16 + lr] += acc[sub][r];
    }
    __syncthreads();
    if (s == 2) {
#pragma unroll
        for (int sub = 0; sub < 4; ++sub)
#pragma unroll
            for (int r = 0; r < 4; ++r) Osh[lg * 4 + r][sub * 16 + lr] += acc[sub][r];
    }
    __syncthreads();
    if (s == 3) {
#pragma unroll
        for (int sub = 0; sub < 4; ++sub) {
#pragma unroll
            for (int r = 0; r < 4; ++r) {
                int i = i0 + lg * 4 + r;
                int j = sub * 16 + lr;
                C[(size_t)i * ODIM + j] = Osh[lg * 4 + r][sub * 16 + lr] + acc[sub][r] + bvec[j];
            }
        }
    }
}

extern "C" void kernel_launch(void* const* d_in, const int* in_sizes, int n_in,
                              void* d_out, int out_size, void* d_ws, size_t ws_size,
                              hipStream_t stream) {
    const float* x      = (const float*)d_in[0];
    const int*   ei     = (const int*)d_in[1];
    const float* eattr  = (const float*)d_in[2];
    const int*   epaths = (const int*)d_in[4];
    const float* Wn     = (const float*)d_in[5];
    const float* bn     = (const float*)d_in[6];
    const float* We     = (const float*)d_in[7];
    const float* be     = (const float*)d_in[8];
    const float* zin    = (const float*)d_in[9];
    const float* zout   = (const float*)d_in[10];
    const float* bsp    = (const float*)d_in[11];
    const float* ev     = (const float*)d_in[12];
    const float* ln1s   = (const float*)d_in[13];
    const float* ln1b   = (const float*)d_in[14];
    const float* Wq     = (const float*)d_in[15];
    const float* bq     = (const float*)d_in[16];
    const float* Wk     = (const float*)d_in[17];
    const float* bk     = (const float*)d_in[18];
    const float* Wv     = (const float*)d_in[19];
    const float* bv     = (const float*)d_in[20];
    const float* Wo     = (const float*)d_in[21];
    const float* bo     = (const float*)d_in[22];
    const float* ln2s   = (const float*)d_in[23];
    const float* ln2b   = (const float*)d_in[24];
    const float* W1     = (const float*)d_in[25];
    const float* b1     = (const float*)d_in[26];
    const float* W2     = (const float*)d_in[27];
    const float* b2     = (const float*)d_in[28];
    const float* Wout   = (const float*)d_in[29];
    const float* bout   = (const float*)d_in[30];

    char* base = (char*)d_ws;
    size_t off = 0;
    auto alloc = [&](size_t bytes) { char* p = base + off; off = (off + bytes + 255) & ~(size_t)255; return p; };
    bf16*  bias   = (bf16*)alloc((size_t)N_NODES * N_NODES * 2);
    float* h      = (float*)alloc((size_t)N_NODES * HDIM * 4);
    bf16*  wT     = (bf16*)alloc((size_t)LPATH * NEDGE * 2);
    int*   deg    = (int*)alloc(2 * N_NODES * 4);
    bf16*  WnT    = (bf16*)alloc((size_t)HDIM * FDIM * 2);
    bf16*  WoutT  = (bf16*)alloc((size_t)ODIM * HDIM * 2);
    bf16*  Wt     = (bf16*)alloc((size_t)NLAYER * 6 * HDIM * HDIM * 2);
    bf16*  y_bf   = (bf16*)alloc((size_t)N_NODES * HDIM * 2);
    bf16*  qfb    = (bf16*)alloc((size_t)NHEAD * 128 * 2 * 512 * 2);
    bf16*  kfb    = (bf16*)alloc((size_t)NHEAD * 128 * 2 * 512 * 2);
    bf16*  vfb    = (bf16*)alloc((size_t)NHEAD * 4 * 64 * 512 * 2);
    bf16*  ob_bf  = (bf16*)alloc((size_t)N_NODES * HDIM * 2);
    bf16*  t1_bf  = (bf16*)alloc((size_t)N_NODES * HDIM * 2);
    int* din = deg;
    int* dout = deg + N_NODES;

    hipMemsetAsync(deg, 0, 2 * N_NODES * sizeof(int), stream);

    k_prep<<<1920, 256, 0, stream>>>(eattr, We, be, ev, ei, din, dout, wT,
                                     Wq, Wk, Wv, Wo, W1, W2, Wn, Wout, Wt, WnT, WoutT);
    k_bias3<<<512, 1024, 0, stream>>>(epaths, wT, bsp, bias);
    k_nmm<<<dim3(8, 32), 256, 0, stream>>>(x, WnT, bn, zin, zout, din, dout, h);

    dim3 gqkv(48, 32);
    dim3 gmm(8, 32);

    for (int lay = 0; lay < NLAYER; ++lay) {
        const bf16* Wt_l = Wt + (size_t)lay * 6 * HDIM * HDIM;
        size_t bOff = (size_t)lay * HDIM;
        k_ln<<<512, 256, 0, stream>>>(h, ln1s + bOff, ln1b + bOff, y_bf);
        k_qkv<<<gqkv, 256, 0, stream>>>(y_bf, Wt_l, bq + bOff, bk + bOff, bv + bOff, qfb, kfb, vfb);
        k_attn2<<<256, 1024, 0, stream>>>(qfb, kfb, vfb, bias, ob_bf);
        k_mm<<<gmm, 1024, 0, stream>>>(ob_bf, Wt_l + (size_t)3 * HDIM * HDIM, bo + bOff, h, h, nullptr, FL_RES | FL_OUTF);
        k_mmln<<<gmm, 1024, 0, stream>>>(h, Wt_l + (size_t)4 * HDIM * HDIM, ln2s + bOff, ln2b + bOff, b1 + bOff, t1_bf);
        k_mm<<<gmm, 1024, 0, stream>>>(t1_bf, Wt_l + (size_t)5 * HDIM * HDIM, b2 + bOff, h, h, nullptr, FL_RES | FL_OUTF);
    }
    k_fout<<<128, 256, 0, stream>>>(h, WoutT, bout, (float*)d_out);
}

// Round 17
// 441.567 us; speedup vs baseline: 1.4471x; 1.0227x over previous
//
#include <hip/hip_runtime.h>
#include <hip/hip_bf16.h>
#include <math.h>

#define N_NODES 2048
#define NEDGE   65536
#define FDIM    128
#define HDIM    512
#define EFD     16
#define EDD     64
#define LPATH   5
#define NLAYER  4
#define NHEAD   8
#define DK      64
#define ODIM    64
#define MAXDEG  64
#define PTOT    4194304
#define LOG2E   1.4426950408889634f

typedef __bf16 bf16;
typedef bf16 bf16x8 __attribute__((ext_vector_type(8)));
typedef bf16 bf16x4 __attribute__((ext_vector_type(4)));
typedef float f32x4 __attribute__((ext_vector_type(4)));
typedef unsigned short u16;

// ---------------- fused prep: blocks [0,256) = edge weights + degrees; [256,1920) = weight transposes ----------------
__global__ __launch_bounds__(256) void k_prep(const float* __restrict__ ea, const float* __restrict__ We,
                                              const float* __restrict__ be, const float* __restrict__ ev,
                                              const int* __restrict__ ei, int* __restrict__ din,
                                              int* __restrict__ dout, bf16* __restrict__ wT,
                                              const float* __restrict__ Wq, const float* __restrict__ Wk,
                                              const float* __restrict__ Wv, const float* __restrict__ Wo,
                                              const float* __restrict__ W1, const float* __restrict__ W2,
                                              const float* __restrict__ Wn, const float* __restrict__ Wout,
                                              bf16* __restrict__ Wt, bf16* __restrict__ WnT,
                                              bf16* __restrict__ WoutT) {
    __shared__ float sM[80];
    __shared__ float sc[8];
    __shared__ float Ls[64][68];
    int t = threadIdx.x;
    int bx = blockIdx.x;
    if (bx < 256) {
        if (t < 80) {
            int i = t / 5, j = t % 5;
            float acc = 0.f;
            for (int k = 0; k < EDD; ++k) acc += We[i * EDD + k] * ev[j * EDD + k];
            sM[t] = acc;
        } else if (t >= 128 && t < 128 + LPATH) {
            int j = t - 128;
            float acc = 0.f;
            for (int k = 0; k < EDD; ++k) acc += be[k] * ev[j * EDD + k];
            sc[j] = acc;
        }
        int e = bx * 256 + t;
        atomicAdd(&dout[ei[e]], 1);
        atomicAdd(&din[ei[NEDGE + e]], 1);
        __syncthreads();
        const float4* p = (const float4*)(ea + (size_t)e * EFD);
        float4 a0 = p[0], a1 = p[1], a2 = p[2], a3 = p[3];
        float a[16] = {a0.x, a0.y, a0.z, a0.w, a1.x, a1.y, a1.z, a1.w,
                       a2.x, a2.y, a2.z, a2.w, a3.x, a3.y, a3.z, a3.w};
        float out[LPATH];
#pragma unroll
        for (int j = 0; j < LPATH; ++j) out[j] = sc[j];
#pragma unroll
        for (int i = 0; i < 16; ++i)
#pragma unroll
            for (int j = 0; j < LPATH; ++j) out[j] += a[i] * sM[i * LPATH + j];
#pragma unroll
        for (int j = 0; j < LPATH; ++j) wT[(size_t)j * NEDGE + e] = (bf16)out[j];
        return;
    }
    int m = (bx - 256) >> 6;
    int q = (bx - 256) & 63;
    int rr = t >> 4, cc = t & 15;
    int nl = t >> 2, kc = t & 3;
    if (m < 24) {
        int lay = m / 6, type = m % 6;
        const float* src = type == 0 ? Wq : type == 1 ? Wk : type == 2 ? Wv : type == 3 ? Wo : type == 4 ? W1 : W2;
        src += (size_t)lay * (HDIM * HDIM);
        int tk = q >> 3, tn = q & 7;
#pragma unroll
        for (int u = 0; u < 4; ++u) {
            float4 v = *(const float4*)(src + (size_t)(tk * 64 + rr + 16 * u) * HDIM + tn * 64 + cc * 4);
            *(float4*)&Ls[rr + 16 * u][cc * 4] = v;
        }
        __syncthreads();
        bf16 tmp[16];
#pragma unroll
        for (int u = 0; u < 16; ++u) tmp[u] = (bf16)Ls[kc * 16 + u][nl];
        bf16* dst = Wt + (size_t)m * (HDIM * HDIM) + (size_t)(tn * 64 + nl) * HDIM + tk * 64 + kc * 16;
        *(bf16x8*)(dst) = *(bf16x8*)&tmp[0];
        *(bf16x8*)(dst + 8) = *(bf16x8*)&tmp[8];
    } else if (m == 24) {
        if (q >= 16) return;
        int tk = q >> 3, tn = q & 7;
#pragma unroll
        for (int u = 0; u < 4; ++u) {
            float4 v = *(const float4*)(Wn + (size_t)(tk * 64 + rr + 16 * u) * HDIM + tn * 64 + cc * 4);
            *(float4*)&Ls[rr + 16 * u][cc * 4] = v;
        }
        __syncthreads();
        bf16 tmp[16];
#pragma unroll
        for (int u = 0; u < 16; ++u) tmp[u] = (bf16)Ls[kc * 16 + u][nl];
        bf16* dst = WnT + (size_t)(tn * 64 + nl) * FDIM + tk * 64 + kc * 16;
        *(bf16x8*)dst = *(bf16x8*)&tmp[0];
        *(bf16x8*)(dst + 8) = *(bf16x8*)&tmp[8];
    } else {
        if (q >= 8) return;
        int tk = q;
#pragma unroll
        for (int u = 0; u < 4; ++u) {
            float4 v = *(const float4*)(Wout + (size_t)(tk * 64 + rr + 16 * u) * ODIM + cc * 4);
            *(float4*)&Ls[rr + 16 * u][cc * 4] = v;
        }
        __syncthreads();
        bf16 tmp[16];
#pragma unroll
        for (int u = 0; u < 16; ++u) tmp[u] = (bf16)Ls[kc * 16 + u][nl];
        bf16* dst = WoutT + (size_t)nl * HDIM + tk * 64 + kc * 16;
        *(bf16x8*)dst = *(bf16x8*)&tmp[0];
        *(bf16x8*)(dst + 8) = *(bf16x8*)&tmp[8];
    }
}

// ---------------- bias: r8 structure (single 8192-pair chunk, spill-free). Output bias * LOG2E ----------------
__global__ __launch_bounds__(1024) void k_bias3(const int* __restrict__ ep, const bf16* __restrict__ wT,
                                                const float* __restrict__ bsp, bf16* __restrict__ bias) {
    __shared__ char lds[163840];
    int t = threadIdx.x;
    size_t basep = (size_t)blockIdx.x * 8192;
    int* ish = (int*)lds;
    const int4* src = (const int4*)(ep + basep * 5);
#pragma unroll
    for (int u = 0; u < 10; ++u) ((int4*)ish)[t + 1024 * u] = src[t + 1024 * u];
    __syncthreads();
    unsigned pa[8], pb[8], pc[8];
#pragma unroll
    for (int r = 0; r < 8; ++r) {
        int p5 = (r * 1024 + t) * 5;
        int e0 = ish[p5], e1 = ish[p5 + 1], e2 = ish[p5 + 2], e3 = ish[p5 + 3], e4 = ish[p5 + 4];
        unsigned mk = (unsigned)(e0 >= 0) | ((unsigned)(e1 >= 0) << 1) | ((unsigned)(e2 >= 0) << 2)
                    | ((unsigned)(e3 >= 0) << 3) | ((unsigned)(e4 >= 0) << 4);
        pa[r] = ((unsigned)e0 & 0xFFFFu) | ((unsigned)e1 << 16);
        pb[r] = ((unsigned)e2 & 0xFFFFu) | ((unsigned)e3 << 16);
        pc[r] = ((unsigned)e4 & 0xFFFFu) | (mk << 16);
    }
    bf16* wsl = (bf16*)lds;
    float csum[8] = {};
#pragma unroll
    for (int l = 0; l < LPATH; ++l) {
        __syncthreads();
#pragma unroll
        for (int u = 0; u < 4; ++u) {
            int o = u * 16384 + t * 16;
            *(bf16x8*)&wsl[o]     = *(const bf16x8*)&wT[(size_t)l * NEDGE + o];
            *(bf16x8*)&wsl[o + 8] = *(const bf16x8*)&wT[(size_t)l * NEDGE + o + 8];
        }
        __syncthreads();
#pragma unroll
        for (int r = 0; r < 8; ++r) {
            unsigned ix = (l == 0) ? (pa[r] & 0xFFFFu) : (l == 1) ? (pa[r] >> 16)
                        : (l == 2) ? (pb[r] & 0xFFFFu) : (l == 3) ? (pb[r] >> 16) : (pc[r] & 0xFFFFu);
            float v = (float)wsl[ix];
            csum[r] += ((pc[r] >> (16 + l)) & 1u) ? v : 0.f;
        }
    }
#pragma unroll
    for (int r = 0; r < 8; ++r) {
        int cnt = __popc((int)((pc[r] >> 16) & 0x1Fu));
        float b = cnt ? (bsp[cnt - 1] + csum[r] / (float)cnt) * LOG2E : 0.f;
        bias[basep + r * 1024 + t] = (bf16)b;
    }
}

// ---------------- layernorm (LN1): wave-per-row, shuffle-only ----------------
__global__ __launch_bounds__(256) void k_ln(const float* __restrict__ h, const float* __restrict__ sc,
                                            const float* __restrict__ bi, bf16* __restrict__ y) {
    int t = threadIdx.x, w = t >> 6, l = t & 63;
    int row = blockIdx.x * 4 + w;
    const float* hp = h + (size_t)row * HDIM + l * 8;
    float4 a = *(const float4*)hp;
    float4 b = *(const float4*)(hp + 4);
    float s = a.x + a.y + a.z + a.w + b.x + b.y + b.z + b.w;
    float q = a.x * a.x + a.y * a.y + a.z * a.z + a.w * a.w
            + b.x * b.x + b.y * b.y + b.z * b.z + b.w * b.w;
#pragma unroll
    for (int m = 1; m < 64; m <<= 1) { s += __shfl_xor(s, m); q += __shfl_xor(q, m); }
    float mean = s * (1.f / HDIM);
    float var = q * (1.f / HDIM) - mean * mean;
    float r = rsqrtf(var + 1e-5f);
    float4 s0 = *(const float4*)(sc + l * 8), s1 = *(const float4*)(sc + l * 8 + 4);
    float4 b0 = *(const float4*)(bi + l * 8), b1 = *(const float4*)(bi + l * 8 + 4);
    float va[8] = {a.x, a.y, a.z, a.w, b.x, b.y, b.z, b.w};
    float ss[8] = {s0.x, s0.y, s0.z, s0.w, s1.x, s1.y, s1.z, s1.w};
    float bb[8] = {b0.x, b0.y, b0.z, b0.w, b1.x, b1.y, b1.z, b1.w};
    bf16x8 o;
#pragma unroll
    for (int c = 0; c < 8; ++c) o[c] = (bf16)((va[c] - mean) * r * ss[c] + bb[c]);
    *(bf16x8*)(y + (size_t)row * HDIM + l * 8) = o;
}

// node projection as MFMA GEMM (K=128, f32 x inline-cast) + degree-embedding epilogue
__global__ __launch_bounds__(256) void k_nmm(const float* __restrict__ x, const bf16* __restrict__ Bt,
                                             const float* __restrict__ bn, const float* __restrict__ zin,
                                             const float* __restrict__ zout, const int* __restrict__ din,
                                             const int* __restrict__ dout, float* __restrict__ h) {
    __shared__ bf16 Bs[8192];
    int t = threadIdx.x, w = t >> 6, l = t & 63, lr = l & 15, lg = l >> 4;
    int j0 = blockIdx.x * 64, i0 = blockIdx.y * 64;
    const bf16* Bp = Bt + (size_t)j0 * FDIM;
#pragma unroll
    for (int rnd = 0; rnd < 4; ++rnd) {
        int tt = rnd * 256 + t;
        int ks = tt >> 8, qq = (tt >> 6) & 3, mm = (tt >> 2) & 15, gg = tt & 3;
        *(bf16x8*)(Bs + tt * 8) = *(const bf16x8*)(Bp + (size_t)(qq * 16 + mm) * FDIM + ks * 32 + gg * 8);
    }
    __syncthreads();
    const float* ap = x + (size_t)(i0 + w * 16 + lr) * FDIM + 8 * lg;
    f32x4 acc[4] = {};
#pragma unroll
    for (int ks = 0; ks < 4; ++ks) {
        float4 f0 = *(const float4*)(ap + ks * 32);
        float4 f1 = *(const float4*)(ap + ks * 32 + 4);
        bf16x8 a;
        a[0] = (bf16)f0.x; a[1] = (bf16)f0.y; a[2] = (bf16)f0.z; a[3] = (bf16)f0.w;
        a[4] = (bf16)f1.x; a[5] = (bf16)f1.y; a[6] = (bf16)f1.z; a[7] = (bf16)f1.w;
        const bf16* bb = Bs + ks * 2048 + lr * 32 + lg * 8;
#pragma unroll
        for (int sub = 0; sub < 4; ++sub)
            acc[sub] = __builtin_amdgcn_mfma_f32_16x16x32_bf16(a, *(const bf16x8*)(bb + sub * 512), acc[sub], 0, 0, 0);
    }
#pragma unroll
    for (int r = 0; r < 4; ++r) {
        int i = i0 + w * 16 + lg * 4 + r;
        int di = min(din[i], MAXDEG - 1), dz = min(dout[i], MAXDEG - 1);
#pragma unroll
        for (int sub = 0; sub < 4; ++sub) {
            int j = j0 + sub * 16 + lr;
            h[(size_t)i * HDIM + j] = acc[sub][r] + bn[j] + zin[(size_t)di * HDIM + j] + zout[(size_t)dz * HDIM + j];
        }
    }
}

// ---------------- fused QKV GEMM (BM=128, 512 threads, 8 waves) -> frag-contiguous q/k/v layouts ----------------
// q pre-scaled by 0.125*LOG2E (attn softmax in exp2 domain)
__global__ __launch_bounds__(512) void k_qkv(const bf16* __restrict__ A, const bf16* __restrict__ Wt_l,
                                             const float* __restrict__ bq, const float* __restrict__ bk,
                                             const float* __restrict__ bv, bf16* __restrict__ qf,
                                             bf16* __restrict__ kf, bf16* __restrict__ vf) {
    __shared__ bf16 Bs[16384];
    int t = threadIdx.x, w = t >> 6, l = t & 63, lr = l & 15, lg = l >> 4;
    int j0 = blockIdx.x * 32, i0 = blockIdx.y * 128;
    int type = j0 >> 9, n0 = j0 & 511;
    const bf16* Bp = Wt_l + (size_t)type * (HDIM * HDIM) + (size_t)n0 * HDIM;
#pragma unroll
    for (int rnd = 0; rnd < 4; ++rnd) {
        int tt = rnd * 512 + t;
        int ks = tt >> 7, qq = (tt >> 6) & 1, mm = (tt >> 2) & 15, gg = tt & 3;
        bf16x8 v = *(const bf16x8*)(Bp + (size_t)(qq * 16 + mm) * HDIM + ks * 32 + gg * 8);
        *(bf16x8*)(Bs + tt * 8) = v;
    }
    __syncthreads();
    const bf16* ap = A + (size_t)(i0 + w * 16 + lr) * HDIM + 8 * lg;
    const float* bvec = (type == 0 ? bq : type == 1 ? bk : bv);
    f32x4 acc[2] = {};
#pragma unroll 4
    for (int ks = 0; ks < 16; ++ks) {
        bf16x8 a  = *(const bf16x8*)(ap + ks * 32);
        const bf16* bb = Bs + ks * 1024 + lr * 32 + lg * 8;
        bf16x8 b0 = *(const bf16x8*)(bb);
        bf16x8 b1 = *(const bf16x8*)(bb + 512);
        acc[0] = __builtin_amdgcn_mfma_f32_16x16x32_bf16(a, b0, acc[0], 0, 0, 0);
        acc[1] = __builtin_amdgcn_mfma_f32_16x16x32_bf16(a, b1, acc[1], 0, 0, 0);
    }
    int h = n0 >> 6;
    if (type < 2) {
        bf16* dst = (type == 0 ? qf : kf);
        int hf = (n0 & 32) >> 5;
        float sc = (type == 0 ? 0.125f * LOG2E : 1.0f);
#pragma unroll
        for (int sub = 0; sub < 2; ++sub) {
#pragma unroll
            for (int r = 0; r < 4; ++r) {
                int i = i0 + w * 16 + lg * 4 + r;
                float v = (acc[sub][r] + bvec[n0 + sub * 16 + lr]) * sc;
                int lgp = sub * 2 + (lr >> 3);
                size_t off = (((size_t)(h * 128 + (i >> 4)) * 2 + hf) << 9) + lgp * 128 + (lg * 4 + r) * 8 + (lr & 7);
                dst[off] = (bf16)v;
            }
        }
    } else {
#pragma unroll
        for (int sub = 0; sub < 2; ++sub) {
#pragma unroll
            for (int r = 0; r < 4; ++r) {
                int node = i0 + w * 16 + lg * 4 + r;
                int dd = (n0 & 63) + sub * 16 + lr;
                float v = acc[sub][r] + bvec[n0 + sub * 16 + lr];
                size_t off = (((size_t)(h * 4 + (dd >> 4)) * 64 + (node >> 5)) << 9)
                           + ((node >> 3) & 3) * 128 + (dd & 15) * 8 + (node & 7);
                vf[off] = (bf16)v;
            }
        }
    }
}

// ---------------- generic bf16 MFMA GEMM, BN=64, 16 waves, 4-way K-split ----------------
#define FL_RES   1
#define FL_GELU  2
#define FL_OUTF  4

__device__ inline float gelu_f(float x) {
    float x3 = x * x * x;
    float u = 0.7978845608028654f * (x + 0.044715f * x3);
    return 0.5f * x * (1.f + tanhf(u));
}

__global__ __launch_bounds__(1024) void k_mm(const bf16* __restrict__ A, const bf16* __restrict__ Bt,
                                             const float* __restrict__ bvec, const float* __restrict__ res,
                                             float* __restrict__ outF, bf16* __restrict__ outB, int flags) {
    __shared__ bf16 Bs[32768];
    __shared__ float Osh[4][16][68];
    int t = threadIdx.x, w = t >> 6, l = t & 63, lr = l & 15, lg = l >> 4;
    int ti = w & 3, s = w >> 2;
    int j0 = blockIdx.x * 64, i0 = blockIdx.y * 64;
    const bf16* Bp = Bt + (size_t)j0 * HDIM;
#pragma unroll
    for (int rnd = 0; rnd < 4; ++rnd) {
        int tt = rnd * 1024 + t;
        int ks = tt >> 8, qq = (tt >> 6) & 3, mm = (tt >> 2) & 15, gg = tt & 3;
        bf16x8 v = *(const bf16x8*)(Bp + (size_t)(qq * 16 + mm) * HDIM + ks * 32 + gg * 8);
        *(bf16x8*)(Bs + tt * 8) = v;
    }
    __syncthreads();
    const bf16* ap = A + (size_t)(i0 + ti * 16 + lr) * HDIM + 8 * lg;
    f32x4 acc[4] = {};
#pragma unroll
    for (int kk = 0; kk < 4; ++kk) {
        int ks = s * 4 + kk;
        bf16x8 a = *(const bf16x8*)(ap + ks * 32);
        const bf16* bb = Bs + ks * 2048 + lr * 32 + lg * 8;
#pragma unroll
        for (int sub = 0; sub < 4; ++sub) {
            bf16x8 b = *(const bf16x8*)(bb + sub * 512);
            acc[sub] = __builtin_amdgcn_mfma_f32_16x16x32_bf16(a, b, acc[sub], 0, 0, 0);
        }
    }
    if (s == 0) {
#pragma unroll
        for (int sub = 0; sub < 4; ++sub)
#pragma unroll
            for (int r = 0; r < 4; ++r) Osh[ti][lg * 4 + r][sub * 16 + lr] = acc[sub][r];
    }
    __syncthreads();
    if (s == 1) {
#pragma unroll
        for (int sub = 0; sub < 4; ++sub)
#pragma unroll
            for (int r = 0; r < 4; ++r) Osh[ti][lg * 4 + r][sub * 16 + lr] += acc[sub][r];
    }
    __syncthreads();
    if (s == 2) {
#pragma unroll
        for (int sub = 0; sub < 4; ++sub)
#pragma unroll
            for (int r = 0; r < 4; ++r) Osh[ti][lg * 4 + r][sub * 16 + lr] += acc[sub][r];
    }
    __syncthreads();
    if (s == 3) {
#pragma unroll
        for (int sub = 0; sub < 4; ++sub) {
#pragma unroll
            for (int r = 0; r < 4; ++r) {
                int i = i0 + ti * 16 + lg * 4 + r;
                int j = j0 + sub * 16 + lr;
                float v = Osh[ti][lg * 4 + r][sub * 16 + lr] + acc[sub][r] + bvec[j];
                if (flags & FL_RES) v += res[(size_t)i * HDIM + j];
                if (flags & FL_GELU) v = gelu_f(v);
                if (flags & FL_OUTF) outF[(size_t)i * HDIM + j] = v;
                else outB[(size_t)i * HDIM + j] = (bf16)v;
            }
        }
    }
}

// ---------------- LN2 + FFN1 fused ----------------
__global__ __launch_bounds__(1024) void k_mmln(const float* __restrict__ h, const bf16* __restrict__ Bt,
                                               const float* __restrict__ lnS, const float* __restrict__ lnB,
                                               const float* __restrict__ bvec, bf16* __restrict__ outB) {
    __shared__ bf16 As[32768];
    __shared__ bf16 Bs[32768];
    __shared__ float Osh[4][16][68];
    __shared__ float sbuf[HDIM], bbuf[HDIM];
    int t = threadIdx.x, w = t >> 6, l = t & 63, lr = l & 15, lg = l >> 4;
    int ti = w & 3, s = w >> 2;
    int j0 = blockIdx.x * 64, i0 = blockIdx.y * 64;
    if (t < HDIM) sbuf[t] = lnS[t];
    else bbuf[t - HDIM] = lnB[t - HDIM];
    const bf16* Bp = Bt + (size_t)j0 * HDIM;
#pragma unroll
    for (int rnd = 0; rnd < 4; ++rnd) {
        int tt = rnd * 1024 + t;
        int ks = tt >> 8, qq = (tt >> 6) & 3, mm = (tt >> 2) & 15, gg = tt & 3;
        *(bf16x8*)(Bs + tt * 8) = *(const bf16x8*)(Bp + (size_t)(qq * 16 + mm) * HDIM + ks * 32 + gg * 8);
    }
    int row = t >> 4, ksc = t & 15;
    const float* hp = h + (size_t)(i0 + row) * HDIM + ksc * 32;
    float4 hv[8];
    float S = 0.f, Q = 0.f;
#pragma unroll
    for (int u = 0; u < 8; ++u) {
        hv[u] = *(const float4*)(hp + u * 4);
        S += hv[u].x + hv[u].y + hv[u].z + hv[u].w;
        Q += hv[u].x * hv[u].x + hv[u].y * hv[u].y + hv[u].z * hv[u].z + hv[u].w * hv[u].w;
    }
#pragma unroll
    for (int m = 1; m < 16; m <<= 1) { S += __shfl_xor(S, m); Q += __shfl_xor(Q, m); }
    float mean = S * (1.f / HDIM);
    float var = Q * (1.f / HDIM) - mean * mean;
    float rr = rsqrtf(var + 1e-5f);
    float ca = rr, cc = -mean * rr;
    __syncthreads();
    {
        bf16 tmp[32];
#pragma unroll
        for (int u = 0; u < 8; ++u) {
            float vv[4] = {hv[u].x, hv[u].y, hv[u].z, hv[u].w};
#pragma unroll
            for (int c = 0; c < 4; ++c) {
                int col = ksc * 32 + u * 4 + c;
                tmp[u * 4 + c] = (bf16)(fmaf(fmaf(vv[c], ca, cc), sbuf[col], bbuf[col]));
            }
        }
        bf16* dst = As + (row >> 4) * 8192 + ksc * 512 + (row & 15) * 32;
#pragma unroll
        for (int u = 0; u < 4; ++u) *(bf16x8*)(dst + u * 8) = *(bf16x8*)&tmp[u * 8];
    }
    __syncthreads();
    const bf16* apl = As + ti * 8192 + lr * 32 + lg * 8;
    f32x4 acc[4] = {};
#pragma unroll
    for (int kk = 0; kk < 4; ++kk) {
        int ks = s * 4 + kk;
        bf16x8 a = *(const bf16x8*)(apl + ks * 512);
        const bf16* bb = Bs + ks * 2048 + lr * 32 + lg * 8;
#pragma unroll
        for (int sub = 0; sub < 4; ++sub)
            acc[sub] = __builtin_amdgcn_mfma_f32_16x16x32_bf16(a, *(const bf16x8*)(bb + sub * 512), acc[sub], 0, 0, 0);
    }
    if (s == 0) {
#pragma unroll
        for (int sub = 0; sub < 4; ++sub)
#pragma unroll
            for (int r = 0; r < 4; ++r) Osh[ti][lg * 4 + r][sub * 16 + lr] = acc[sub][r];
    }
    __syncthreads();
    if (s == 1) {
#pragma unroll
        for (int sub = 0; sub < 4; ++sub)
#pragma unroll
            for (int r = 0; r < 4; ++r) Osh[ti][lg * 4 + r][sub * 16 + lr] += acc[sub][r];
    }
    __syncthreads();
    if (s == 2) {
#pragma unroll
        for (int sub = 0; sub < 4; ++sub)
#pragma unroll
            for (int r = 0; r < 4; ++r) Osh[ti][lg * 4 + r][sub * 16 + lr] += acc[sub][r];
    }
    __syncthreads();
    if (s == 3) {
#pragma unroll
        for (int sub = 0; sub < 4; ++sub) {
#pragma unroll
            for (int r = 0; r < 4; ++r) {
                int i = i0 + ti * 16 + lg * 4 + r;
                int j = j0 + sub * 16 + lr;
                float v = gelu_f(Osh[ti][lg * 4 + r][sub * 16 + lr] + acc[sub][r] + bvec[j]);
                outB[(size_t)i * HDIM + j] = (bf16)v;
            }
        }
    }
}

// ---------------- attention: swapped-QK flash, exp2-domain softmax, deferred cross-lane reductions ----------------
__global__ __launch_bounds__(1024) void k_attn2(const bf16* __restrict__ qf, const bf16* __restrict__ kf,
                                                const bf16* __restrict__ vf, const bf16* __restrict__ biasb,
                                                bf16* __restrict__ ob) {
    __shared__ char Pb[16 * 1024];
    __shared__ float Osh[4][64][17];
    __shared__ float Msh[4][4][16], Lsh[4][4][16];
    int t = threadIdx.x, w = t >> 6, l = t & 63, lr = l & 15, lg = l >> 4;
    int ti = w & 3, s = w >> 2;
    int bid = blockIdx.x;
    int wid = (bid & 7) * 32 + (bid >> 3);
    int i0 = (wid >> 3) * 64, hh = wid & 7;
    int irow = i0 + ti * 16;

    const bf16* qb = qf + (((size_t)(hh * 128 + (irow >> 4)) * 2) << 9) + l * 8;
    bf16x8 qy0 = *(const bf16x8*)(qb);
    bf16x8 qy1 = *(const bf16x8*)(qb + 512);

    char* pwr = Pb + w * 1024 + lr * 64;
    unsigned kx = (unsigned)(lr & 6) << 3;

    float m_run = -3e38f, l_run = 0.f;
    f32x4 oacc[4] = {};

    int jb0 = s * 512;
    const bf16* kbp = kf + (((size_t)(hh * 128 + (jb0 >> 4)) * 2) << 9) + l * 8;
    bf16x8 ka0 = *(const bf16x8*)(kbp);
    bf16x8 ka1 = *(const bf16x8*)(kbp + 512);
    bf16x8 ka2 = *(const bf16x8*)(kbp + 1024);
    bf16x8 ka3 = *(const bf16x8*)(kbp + 1536);
    const bf16* bpp = biasb + (size_t)(irow + lr) * N_NODES + jb0 + lg * 4;
    bf16x4 ba0 = *(const bf16x4*)(bpp);
    bf16x4 ba1 = *(const bf16x4*)(bpp + 16);

    for (int it = 0; it < 16; ++it) {
        int jb = s * 512 + it * 32;
        const bf16* vb = vf + (((size_t)(hh * 4) * 64 + (jb >> 5)) << 9) + l * 8;
        bf16x8 vx0 = *(const bf16x8*)(vb);
        bf16x8 vx1 = *(const bf16x8*)(vb + 32768);
        bf16x8 vx2 = *(const bf16x8*)(vb + 65536);
        bf16x8 vx3 = *(const bf16x8*)(vb + 98304);
        bf16x8 kn0, kn1, kn2, kn3;
        bf16x4 bn0, bn1;
        if (it < 15) {
            int jn = jb + 32;
            const bf16* kbn = kf + (((size_t)(hh * 128 + (jn >> 4)) * 2) << 9) + l * 8;
            kn0 = *(const bf16x8*)(kbn);
            kn1 = *(const bf16x8*)(kbn + 512);
            kn2 = *(const bf16x8*)(kbn + 1024);
            kn3 = *(const bf16x8*)(kbn + 1536);
            const bf16* bpn = biasb + (size_t)(irow + lr) * N_NODES + jn + lg * 4;
            bn0 = *(const bf16x4*)(bpn);
            bn1 = *(const bf16x4*)(bpn + 16);
        }

        f32x4 s0v = {}, s1v = {};
        __builtin_amdgcn_s_setprio(1);
        s0v = __builtin_amdgcn_mfma_f32_16x16x32_bf16(ka0, qy0, s0v, 0, 0, 0);
        s0v = __builtin_amdgcn_mfma_f32_16x16x32_bf16(ka1, qy1, s0v, 0, 0, 0);
        s1v = __builtin_amdgcn_mfma_f32_16x16x32_bf16(ka2, qy0, s1v, 0, 0, 0);
        s1v = __builtin_amdgcn_mfma_f32_16x16x32_bf16(ka3, qy1, s1v, 0, 0, 0);
        __builtin_amdgcn_s_setprio(0);

        float p0[4], p1[4];
        float mt = -3e38f;
#pragma unroll
        for (int r = 0; r < 4; ++r) {
            p0[r] = s0v[r] + (float)ba0[r];
            p1[r] = s1v[r] + (float)ba1[r];
            mt = fmaxf(mt, fmaxf(p0[r], p1[r]));
        }
        if (!__all(mt <= m_run + 11.5416f)) {
            mt = fmaxf(mt, __shfl_xor(mt, 16));
            mt = fmaxf(mt, __shfl_xor(mt, 32));
            float mn = fmaxf(m_run, mt);
            float alpha = exp2f(m_run - mn);
            l_run *= alpha;
#pragma unroll
            for (int d = 0; d < 4; ++d) oacc[d] *= alpha;
            m_run = mn;
        }
        float ps = 0.f;
        bf16x4 pk0, pk1;
#pragma unroll
        for (int r = 0; r < 4; ++r) {
            p0[r] = exp2f(p0[r] - m_run);
            p1[r] = exp2f(p1[r] - m_run);
            ps += p0[r] + p1[r];
            pk0[r] = (bf16)p0[r];
            pk1[r] = (bf16)p1[r];
        }
        l_run += ps;

        *(bf16x4*)(pwr + ((lg * 8) ^ kx)) = pk0;
        *(bf16x4*)(pwr + ((32 + lg * 8) ^ kx)) = pk1;
        asm volatile("s_waitcnt lgkmcnt(0)" ::: "memory");
        __builtin_amdgcn_sched_barrier(0x20);
        bf16x8 py = *(bf16x8*)(Pb + w * 1024 + lr * 64 + ((lg * 16) ^ kx));
        __builtin_amdgcn_s_setprio(1);
        oacc[0] = __builtin_amdgcn_mfma_f32_16x16x32_bf16(vx0, py, oacc[0], 0, 0, 0);
        oacc[1] = __builtin_amdgcn_mfma_f32_16x16x32_bf16(vx1, py, oacc[1], 0, 0, 0);
        oacc[2] = __builtin_amdgcn_mfma_f32_16x16x32_bf16(vx2, py, oacc[2], 0, 0, 0);
        oacc[3] = __builtin_amdgcn_mfma_f32_16x16x32_bf16(vx3, py, oacc[3], 0, 0, 0);
        __builtin_amdgcn_s_setprio(0);
        ka0 = kn0; ka1 = kn1; ka2 = kn2; ka3 = kn3;
        ba0 = bn0; ba1 = bn1;
    }

    l_run += __shfl_xor(l_run, 16);
    l_run += __shfl_xor(l_run, 32);

    __syncthreads();
    if (lg == 0) { Msh[ti][s][lr] = m_run; Lsh[ti][s][lr] = l_run; }
    __syncthreads();
    float m0 = Msh[ti][0][lr], m1 = Msh[ti][1][lr], m2 = Msh[ti][2][lr], m3 = Msh[ti][3][lr];
    float mtot = fmaxf(fmaxf(m0, m1), fmaxf(m2, m3));
    float l_tot = Lsh[ti][0][lr] * exp2f(m0 - mtot) + Lsh[ti][1][lr] * exp2f(m1 - mtot)
                + Lsh[ti][2][lr] * exp2f(m2 - mtot) + Lsh[ti][3][lr] * exp2f(m3 - mtot);
    float fac = exp2f(m_run - mtot);
#pragma unroll
    for (int d = 0; d < 4; ++d) oacc[d] *= fac;
    if (s == 0) {
#pragma unroll
        for (int db = 0; db < 4; ++db)
#pragma unroll
            for (int r = 0; r < 4; ++r) Osh[ti][db * 16 + lg * 4 + r][lr] = oacc[db][r];
    }
    __syncthreads();
    if (s == 1) {
#pragma unroll
        for (int db = 0; db < 4; ++db)
#pragma unroll
            for (int r = 0; r < 4; ++r) Osh[ti][db * 16 + lg * 4 + r][lr] += oacc[db][r];
    }
    __syncthreads();
    if (s == 2) {
#pragma unroll
        for (int db = 0; db < 4; ++db)
#pragma unroll
            for (int r = 0; r < 4; ++r) Osh[ti][db * 16 + lg * 4 + r][lr] += oacc[db][r];
    }
    __syncthreads();
    if (s == 3) {
        float inv = 1.f / l_tot;
#pragma unroll
        for (int db = 0; db < 4; ++db) {
            bf16x4 o4;
#pragma unroll
            for (int r = 0; r < 4; ++r)
                o4[r] = (bf16)((Osh[ti][db * 16 + lg * 4 + r][lr] + oacc[db][r]) * inv);
            *(bf16x4*)(ob + (size_t)(irow + lr) * HDIM + hh * DK + db * 16 + lg * 4) = o4;
        }
    }
}

// ---------------- final projection: MFMA, 16-row tiles, 4-way K-split ----------------
__global__ __launch_bounds__(256) void k_fout(const float* __restrict__ h, const bf16* __restrict__ Bt,
                                              const float* __restrict__ bvec, float* __restrict__ C) {
    __shared__ float Osh[16][68];
    int t = threadIdx.x, s = t >> 6, l = t & 63, lr = l & 15, lg = l >> 4;
    int i0 = blockIdx.x * 16;
    const float* ap = h + (size_t)(i0 + lr) * HDIM + s * 128 + lg * 8;
    f32x4 acc[4] = {};
#pragma unroll
    for (int kk = 0; kk < 4; ++kk) {
        float4 f0 = *(const float4*)(ap + kk * 32);
        float4 f1 = *(const float4*)(ap + kk * 32 + 4);
        bf16x8 a;
        a[0] = (bf16)f0.x; a[1] = (bf16)f0.y; a[2] = (bf16)f0.z; a[3] = (bf16)f0.w;
        a[4] = (bf16)f1.x; a[5] = (bf16)f1.y; a[6] = (bf16)f1.z; a[7] = (bf16)f1.w;
#pragma unroll
        for (int sub = 0; sub < 4; ++sub) {
            bf16x8 b = *(const bf16x8*)(Bt + (size_t)(sub * 16 + lr) * HDIM + s * 128 + kk * 32 + lg * 8);
            acc[sub] = __builtin_amdgcn_mfma_f32_16x16x32_bf16(a, b, acc[sub], 0, 0, 0);
        }
    }
    if (s == 0) {
#pragma unroll
        for (int sub = 0; sub < 4; ++sub)
#pragma unroll
            for (int r = 0; r < 4; ++r) Osh[lg * 4 + r][sub * 16 + lr] = acc[sub][r];
    }
    __syncthreads();
    if (s == 1) {
#pragma unroll
        for (int sub = 0; sub < 4; ++sub)
#pragma unroll
            for (int r = 0; r < 4; ++r) Osh[lg * 4 + r][sub * 16 + lr] += acc[sub][r];
    }
    __syncthreads();
    if (s == 2) {
#pragma unroll
        for (int sub = 0; sub < 4; ++sub)
#pragma unroll
            for (int r = 0; r < 4; ++r) Osh[lg * 4 + r][sub * 16 + lr] += acc[sub][r];
    }
    __syncthreads();
    if (s == 3) {
#pragma unroll
        for (int sub = 0; sub < 4; ++sub) {
#pragma unroll
            for (int r = 0; r < 4; ++r) {
                int i = i0 + lg * 4 + r;
                int j = sub * 16 + lr;
                C[(size_t)i * ODIM + j] = Osh[lg * 4 + r][sub * 16 + lr] + acc[sub][r] + bvec[j];
            }
        }
    }
}

extern "C" void kernel_launch(void* const* d_in, const int* in_sizes, int n_in,
                              void* d_out, int out_size, void* d_ws, size_t ws_size,
                              hipStream_t stream) {
    const float* x      = (const float*)d_in[0];
    const int*   ei     = (const int*)d_in[1];
    const float* eattr  = (const float*)d_in[2];
    const int*   epaths = (const int*)d_in[4];
    const float* Wn     = (const float*)d_in[5];
    const float* bn     = (const float*)d_in[6];
    const float* We     = (const float*)d_in[7];
    const float* be     = (const float*)d_in[8];
    const float* zin    = (const float*)d_in[9];
    const float* zout   = (const float*)d_in[10];
    const float* bsp    = (const float*)d_in[11];
    const float* ev     = (const float*)d_in[12];
    const float* ln1s   = (const float*)d_in[13];
    const float* ln1b   = (const float*)d_in[14];
    const float* Wq     = (const float*)d_in[15];
    const float* bq     = (const float*)d_in[16];
    const float* Wk     = (const float*)d_in[17];
    const float* bk     = (const float*)d_in[18];
    const float* Wv     = (const float*)d_in[19];
    const float* bv     = (const float*)d_in[20];
    const float* Wo     = (const float*)d_in[21];
    const float* bo     = (const float*)d_in[22];
    const float* ln2s   = (const float*)d_in[23];
    const float* ln2b   = (const float*)d_in[24];
    const float* W1     = (const float*)d_in[25];
    const float* b1     = (const float*)d_in[26];
    const float* W2     = (const float*)d_in[27];
    const float* b2     = (const float*)d_in[28];
    const float* Wout   = (const float*)d_in[29];
    const float* bout   = (const float*)d_in[30];

    char* base = (char*)d_ws;
    size_t off = 0;
    auto alloc = [&](size_t bytes) { char* p = base + off; off = (off + bytes + 255) & ~(size_t)255; return p; };
    bf16*  bias   = (bf16*)alloc((size_t)N_NODES * N_NODES * 2);
    float* h      = (float*)alloc((size_t)N_NODES * HDIM * 4);
    bf16*  wT     = (bf16*)alloc((size_t)LPATH * NEDGE * 2);
    int*   deg    = (int*)alloc(2 * N_NODES * 4);
    bf16*  WnT    = (bf16*)alloc((size_t)HDIM * FDIM * 2);
    bf16*  WoutT  = (bf16*)alloc((size_t)ODIM * HDIM * 2);
    bf16*  Wt     = (bf16*)alloc((size_t)NLAYER * 6 * HDIM * HDIM * 2);
    bf16*  y_bf   = (bf16*)alloc((size_t)N_NODES * HDIM * 2);
    bf16*  qfb    = (bf16*)alloc((size_t)NHEAD * 128 * 2 * 512 * 2);
    bf16*  kfb    = (bf16*)alloc((size_t)NHEAD * 128 * 2 * 512 * 2);
    bf16*  vfb    = (bf16*)alloc((size_t)NHEAD * 4 * 64 * 512 * 2);
    bf16*  ob_bf  = (bf16*)alloc((size_t)N_NODES * HDIM * 2);
    bf16*  t1_bf  = (bf16*)alloc((size_t)N_NODES * HDIM * 2);
    int* din = deg;
    int* dout = deg + N_NODES;

    hipMemsetAsync(deg, 0, 2 * N_NODES * sizeof(int), stream);

    k_prep<<<1920, 256, 0, stream>>>(eattr, We, be, ev, ei, din, dout, wT,
                                     Wq, Wk, Wv, Wo, W1, W2, Wn, Wout, Wt, WnT, WoutT);
    k_bias3<<<512, 1024, 0, stream>>>(epaths, wT, bsp, bias);
    k_nmm<<<dim3(8, 32), 256, 0, stream>>>(x, WnT, bn, zin, zout, din, dout, h);

    dim3 gqkv(48, 16);
    dim3 gmm(8, 32);

    for (int lay = 0; lay < NLAYER; ++lay) {
        const bf16* Wt_l = Wt + (size_t)lay * 6 * HDIM * HDIM;
        size_t bOff = (size_t)lay * HDIM;
        k_ln<<<512, 256, 0, stream>>>(h, ln1s + bOff, ln1b + bOff, y_bf);
        k_qkv<<<gqkv, 512, 0, stream>>>(y_bf, Wt_l, bq + bOff, bk + bOff, bv + bOff, qfb, kfb, vfb);
        k_attn2<<<256, 1024, 0, stream>>>(qfb, kfb, vfb, bias, ob_bf);
        k_mm<<<gmm, 1024, 0, stream>>>(ob_bf, Wt_l + (size_t)3 * HDIM * HDIM, bo + bOff, h, h, nullptr, FL_RES | FL_OUTF);
        k_mmln<<<gmm, 1024, 0, stream>>>(h, Wt_l + (size_t)4 * HDIM * HDIM, ln2s + bOff, ln2b + bOff, b1 + bOff, t1_bf);
        k_mm<<<gmm, 1024, 0, stream>>>(t1_bf, Wt_l + (size_t)5 * HDIM * HDIM, b2 + bOff, h, h, nullptr, FL_RES | FL_OUTF);
    }
    k_fout<<<128, 256, 0, stream>>>(h, WoutT, bout, (float*)d_out);
}